// Round 1
// 4057.814 us; speedup vs baseline: 1.1094x; 1.1094x over previous
//
#include <hip/hip_runtime.h>
#include <stdint.h>

#define B_ 4
#define T_ 4096
#define D_ 1024
#define H_ 16
#define HD_ 64
#define C_ 64
#define N_ 64
#define BT_ (B_*T_)

typedef unsigned short u16;

__device__ __forceinline__ float wave_sum(float v){
  #pragma unroll
  for(int off=32; off>0; off>>=1) v += __shfl_down(v, off);
  return __shfl(v, 0);
}

// ---------------------------------------------------------------------------
// K1: per-(b,t): invn = 1/||x_head||, gate/beta/decay projections
// ---------------------------------------------------------------------------
__global__ __launch_bounds__(256) void k_small(const float* __restrict__ x,
    const float* __restrict__ wg, const float* __restrict__ wb, const float* __restrict__ wa,
    const float* __restrict__ dtb, const float* __restrict__ alog,
    float* __restrict__ invn, float* __restrict__ gate, float* __restrict__ beta,
    float* __restrict__ dec){
  int row = blockIdx.x;            // b*T + t
  __shared__ float xs[D_];
  {
    int i0 = threadIdx.x*4;
    float4 u = *(const float4*)(x + (size_t)row*D_ + i0);
    xs[i0+0]=u.x; xs[i0+1]=u.y; xs[i0+2]=u.z; xs[i0+3]=u.w;
  }
  __syncthreads();
  int w = threadIdx.x>>6, l = threadIdx.x&63;
  #pragma unroll
  for(int i=0;i<4;++i){
    int h = w*4+i;
    float v = xs[h*64+l];
    float ss = wave_sum(v*v);
    float dg=0.f,db=0.f,da=0.f;
    #pragma unroll
    for(int k16=0;k16<16;++k16){
      int k = l + 64*k16;
      float xv = xs[k];
      dg += xv*wg[k*H_+h];
      db += xv*wb[k*H_+h];
      da += xv*wa[k*H_+h];
    }
    dg = wave_sum(dg); db = wave_sum(db); da = wave_sum(da);
    if(l==0){
      int o = row*H_+h;
      invn[o] = 1.f/fmaxf(sqrtf(ss),1e-12f);
      gate[o] = 1.f/(1.f+expf(-dg));
      beta[o] = 1.f/(1.f+expf(-db));
      float z = da + dtb[h];
      float sp = (z>20.f)? z : log1pf(expf(z));
      dec[o] = -expf(alog[h])*sp;
    }
  }
}

// ---------------------------------------------------------------------------
// K2: C(f32) = A(f32) @ B(f32), 128x128 tile, BK=8, 8x8/thread
// ---------------------------------------------------------------------------
#define BM 128
#define BN 128
#define BK 8
__global__ __launch_bounds__(256) void k_gemm_bb(const float* __restrict__ A,
    const float* __restrict__ Bw, float* __restrict__ Cc, int M, int Nn, int K){
  __shared__ float As[BK][BM];
  __shared__ float Bs[BK][BN];
  int tid = threadIdx.x;
  int tx = tid & 15, ty = tid >> 4;
  int m0 = blockIdx.y*BM, n0 = blockIdx.x*BN;
  int arow = tid>>1, ak = (tid&1)*4;
  int bk = tid>>5, bcol = (tid&31)*4;
  float acc[8][8] = {};
  for(int k0=0;k0<K;k0+=BK){
    float4 ua = *(const float4*)(A  + (size_t)(m0+arow)*K + k0+ak);
    float4 ub = *(const float4*)(Bw + (size_t)(k0+bk)*Nn + n0+bcol);
    __syncthreads();
    As[ak+0][arow]=ua.x; As[ak+1][arow]=ua.y;
    As[ak+2][arow]=ua.z; As[ak+3][arow]=ua.w;
    Bs[bk][bcol+0]=ub.x; Bs[bk][bcol+1]=ub.y;
    Bs[bk][bcol+2]=ub.z; Bs[bk][bcol+3]=ub.w;
    __syncthreads();
    #pragma unroll
    for(int kk=0;kk<BK;++kk){
      float a[8], b[8];
      *(float4*)&a[0] = *(const float4*)&As[kk][ty*8];
      *(float4*)&a[4] = *(const float4*)&As[kk][ty*8+4];
      *(float4*)&b[0] = *(const float4*)&Bs[kk][tx*8];
      *(float4*)&b[4] = *(const float4*)&Bs[kk][tx*8+4];
      #pragma unroll
      for(int i=0;i<8;++i)
        #pragma unroll
        for(int j=0;j<8;++j) acc[i][j] += a[i]*b[j];
    }
  }
  for(int i=0;i<8;++i){
    float4 v0 = {acc[i][0],acc[i][1],acc[i][2],acc[i][3]};
    float4 v1 = {acc[i][4],acc[i][5],acc[i][6],acc[i][7]};
    *(float4*)(Cc + (size_t)(m0+ty*8+i)*Nn + n0+tx*8)   = v0;
    *(float4*)(Cc + (size_t)(m0+ty*8+i)*Nn + n0+tx*8+4) = v1;
  }
}

// ---------------------------------------------------------------------------
// K6: Out(f32) = resid(f32) + A(f32) @ B(f32)
// ---------------------------------------------------------------------------
__global__ __launch_bounds__(256) void k_gemm_out(const float* __restrict__ A,
    const float* __restrict__ Bw, const float* __restrict__ resid, float* __restrict__ Outp,
    int M, int Nn, int K){
  __shared__ float As[BK][BM];
  __shared__ float Bs[BK][BN];
  int tid = threadIdx.x;
  int tx = tid & 15, ty = tid >> 4;
  int m0 = blockIdx.y*BM, n0 = blockIdx.x*BN;
  int arow = tid>>1, ak = (tid&1)*4;
  int bk = tid>>5, bcol = (tid&31)*4;
  float acc[8][8] = {};
  for(int k0=0;k0<K;k0+=BK){
    float4 fa = *(const float4*)(A + (size_t)(m0+arow)*K + k0+ak);
    float4 ub = *(const float4*)(Bw + (size_t)(k0+bk)*Nn + n0+bcol);
    __syncthreads();
    As[ak+0][arow]=fa.x; As[ak+1][arow]=fa.y; As[ak+2][arow]=fa.z; As[ak+3][arow]=fa.w;
    Bs[bk][bcol+0]=ub.x; Bs[bk][bcol+1]=ub.y;
    Bs[bk][bcol+2]=ub.z; Bs[bk][bcol+3]=ub.w;
    __syncthreads();
    #pragma unroll
    for(int kk=0;kk<BK;++kk){
      float a[8], b[8];
      *(float4*)&a[0] = *(const float4*)&As[kk][ty*8];
      *(float4*)&a[4] = *(const float4*)&As[kk][ty*8+4];
      *(float4*)&b[0] = *(const float4*)&Bs[kk][tx*8];
      *(float4*)&b[4] = *(const float4*)&Bs[kk][tx*8+4];
      #pragma unroll
      for(int i=0;i<8;++i)
        #pragma unroll
        for(int j=0;j<8;++j) acc[i][j] += a[i]*b[j];
    }
  }
  for(int i=0;i<8;++i){
    size_t ro = (size_t)(m0+ty*8+i)*Nn + n0+tx*8;
    float4 r0 = *(const float4*)(resid + ro);
    float4 r1 = *(const float4*)(resid + ro + 4);
    float4 s0, s1;
    s0.x=acc[i][0]+r0.x; s0.y=acc[i][1]+r0.y;
    s0.z=acc[i][2]+r0.z; s0.w=acc[i][3]+r0.w;
    s1.x=acc[i][4]+r1.x; s1.y=acc[i][5]+r1.y;
    s1.z=acc[i][6]+r1.z; s1.w=acc[i][7]+r1.w;
    *(float4*)(Outp + ro)     = s0;
    *(float4*)(Outp + ro + 4) = s1;
  }
}

// ---------------------------------------------------------------------------
// K3: per-chunk: cum, KK, forward substitution -> v_corr (in-place in vbuf),
//     wk_cd -> wkop
// ---------------------------------------------------------------------------
__global__ __launch_bounds__(256) void k_chunk(const float* __restrict__ x,
    const float* __restrict__ invn, const float* __restrict__ beta_g,
    const float* __restrict__ dec_g, float* __restrict__ cum_g,
    float* __restrict__ vbuf, float* __restrict__ wkop){
  int bid = blockIdx.x;                  // b*H*N + h*N + n
  int n = bid & 63; int h = (bid>>6) & 15; int b = bid>>10;
  int t0 = n*C_;
  __shared__ float sm[12608];
  float* WK = sm;            // 64*65 (padded), aliased by XV later
  float* KK = sm+4160;       // 64*64
  float* XW = sm+8256;       // 64*64
  float* BS = sm+12352;      // 64
  float* CU = sm+12416;      // 64
  float* DE = sm+12480;      // 64
  float* GS = sm+12544;      // 64
  float* XV = WK;            // 4096 over WK region (stride 64)
  int tid = threadIdx.x, w = tid>>6, l = tid&63;
  // A: stage shifted normalized keys + beta + decay
  #pragma unroll
  for(int it=0; it<16; ++it){
    int idx = tid + 256*it; int c = idx>>6, dd = idx&63;
    int tw = t0+c-1;
    float wv = 0.f;
    if(tw>=0){
      size_t rr = (size_t)(b*T_+tw);
      wv = x[rr*D_ + h*64 + dd] * invn[rr*H_ + h];
    }
    WK[c*65+dd] = wv;
  }
  if(tid<64){
    size_t rr = (size_t)(b*T_+t0+tid);
    BS[tid] = beta_g[rr*H_+h];
    GS[tid] = dec_g[rr*H_+h];
  }
  __syncthreads();
  // B: inclusive cumsum of decay (wave 0)
  if(w==0){
    float xg = GS[l];
    #pragma unroll
    for(int off=1; off<64; off<<=1){
      float y = __shfl_up(xg, off);
      if(l>=off) xg += y;
    }
    CU[l]=xg; DE[l]=expf(xg);
    cum_g[(size_t)bid*64 + l] = xg;
  }
  __syncthreads();
  // C: KK[i][j] = beta_i * (wk_i . wk_j) * L[i][j], strict lower
  float wkj[64];
  #pragma unroll
  for(int dd=0; dd<64; ++dd) wkj[dd] = WK[l*65+dd];
  #pragma unroll 1
  for(int it=0; it<16; ++it){
    int i = w + 4*it;
    float aw=0.f;
    #pragma unroll
    for(int dd=0; dd<64; ++dd) aw += WK[i*65+dd]*wkj[dd];
    KK[i*64+l] = (l<i) ? (BS[i]*aw*expf(CU[i]-CU[l])) : 0.f;
  }
  __syncthreads();
  // D: capture rhs into regs, then write XV (over WK), XW
  float rv[16], rw[16];
  #pragma unroll
  for(int it=0; it<16; ++it){
    int i = w + 4*it;
    rw[it] = WK[i*65+l]*BS[i]*DE[i];
    rv[it] = vbuf[(size_t)(b*T_+t0+i)*D_ + h*64 + l]*BS[i];
  }
  __syncthreads();
  #pragma unroll
  for(int it=0; it<16; ++it){
    int i = w + 4*it;
    XV[i*64+l] = rv[it];
    XW[i*64+l] = rw[it];
  }
  __syncthreads();
  // E: forward substitution (I + strict_lower(KK)) X = rhs (waves 0,1)
  if(w<2){
    float* Xc = (w==0) ? XV : XW;
    for(int i=1;i<64;++i){
      float acc = Xc[i*64+l];
      for(int k=0;k<i;++k) acc -= KK[i*64+k]*Xc[k*64+l];
      Xc[i*64+l] = acc;
    }
  }
  __syncthreads();
  // F: write v_corr (in place), wk_cd
  #pragma unroll
  for(int it=0; it<16; ++it){
    int i = w + 4*it;
    vbuf[(size_t)(b*T_+t0+i)*D_ + h*64 + l] = XV[i*64+l];
    wkop[(size_t)bid*4096 + i*64 + l]       = XW[i*64+l];
  }
}

// ---------------------------------------------------------------------------
// K4 v3: sequential scan per (b,h), 1024 threads (16 waves -> 4 waves/SIMD).
//   Same algorithm as v2 but 4x the TLP for latency hiding; INV/CU LDS
//   buffers eliminated (invn folded into prefetch, DW/DEc computed directly
//   from prefetched cum values) -> one staging barrier instead of two.
//   per chunk: v_new (in-place vbuf), opart (overwrites wkop), S update+clip.
// ---------------------------------------------------------------------------
__global__ __launch_bounds__(1024, 4) void k_scan(const float* __restrict__ x,
    const float* __restrict__ invn_g, const float* __restrict__ cum_g,
    float* __restrict__ vbuf, float* __restrict__ wkop){
  int bh = blockIdx.x;  // b*H + h
  int b = bh>>4, h = bh&15;
  __shared__ float sm[12496];
  float* S   = sm;          // 64x64 state
  float* WCD = sm+4096;     // wkcd chunk; later VNS (= v_new * DW * inv-shift)
  float* RK  = sm+8192;     // rk chunk (pre-scaled by invn)
  float* DW  = sm+12288;    // 64: exp(last-cum)
  float* DEc = sm+12352;    // 64: exp(cum)
  float* PREV= sm+12416;    // 64: prev chunk's last rk row (scaled)
  float* P   = sm+12480;    // 16
  int tid = threadIdx.x, w = tid>>6, l = tid&63;

  #pragma unroll
  for(int it=0;it<4;++it) S[tid+1024*it]=0.f;
  if(tid<64) PREV[tid]=0.f;

  // prologue: prefetch chunk 0 into regs
  float4 pW, pR;
  float pV[4], pC=0.f, pLast=0.f, pIv=0.f;
  {
    size_t base0 = (size_t)bh*N_*4096;
    pW = *(const float4*)(wkop + base0 + (size_t)tid*4);
    int c = tid>>4, c4 = (tid&15)*4;
    pR = *(const float4*)(x + (size_t)(b*T_+c)*D_ + h*64 + c4);
    pIv = invn_g[(size_t)(b*T_+c)*H_ + h];
    #pragma unroll
    for(int it=0;it<4;++it)
      pV[it] = vbuf[(size_t)(b*T_+4*w+it)*D_ + h*64 + l];
    if(tid<64){
      pC    = cum_g[(size_t)bh*N_*64 + tid];
      pLast = cum_g[(size_t)bh*N_*64 + 63];
    }
  }
  __syncthreads();

  for(int n=0;n<N_;++n){
    int t0 = n*C_;
    size_t base = ((size_t)bh*N_ + n)*4096;
    // stage: WCD, RK (scaled), DW/DEc — single barrier
    *(float4*)(WCD + (size_t)tid*4) = pW;
    {
      float4 r = pR;
      r.x*=pIv; r.y*=pIv; r.z*=pIv; r.w*=pIv;
      *(float4*)(RK + (size_t)tid*4) = r;
    }
    if(tid<64){
      DW[tid]  = expf(pLast - pC);
      DEc[tid] = expf(pC);
    }
    __syncthreads();

    // consume pV into accumulators, then prefetch chunk n+1
    float vn[4];
    #pragma unroll
    for(int it=0;it<4;++it) vn[it]=pV[it];
    if(n+1 < N_){
      int t1 = t0 + C_;
      size_t base1 = base + 4096;
      pW = *(const float4*)(wkop + base1 + (size_t)tid*4);
      int c = tid>>4, c4=(tid&15)*4;
      pR = *(const float4*)(x + (size_t)(b*T_+t1+c)*D_ + h*64 + c4);
      pIv = invn_g[(size_t)(b*T_+t1+c)*H_ + h];
      #pragma unroll
      for(int it=0;it<4;++it)
        pV[it] = vbuf[(size_t)(b*T_+t1+4*w+it)*D_ + h*64 + l];
      if(tid<64){
        pC    = cum_g[((size_t)bh*N_+n+1)*64 + tid];
        pLast = cum_g[((size_t)bh*N_+n+1)*64 + 63];
      }
    }

    // s_col = column l of S_pre
    float s_col[64];
    #pragma unroll
    for(int k=0;k<64;++k) s_col[k]=S[k*64+l];

    // v_new = v_corr - wkcd @ S_pre ; opart = exp(cum)*(rk @ S_pre)
    #pragma unroll
    for(int it=0;it<4;++it){
      int c = 4*w+it;
      float a = vn[it], o = 0.f;
      #pragma unroll
      for(int d4=0;d4<16;++d4){
        float4 wv = *(const float4*)&WCD[c*64+4*d4];
        float4 rv = *(const float4*)&RK [c*64+4*d4];
        a -= wv.x*s_col[4*d4]+wv.y*s_col[4*d4+1]+wv.z*s_col[4*d4+2]+wv.w*s_col[4*d4+3];
        o += rv.x*s_col[4*d4]+rv.y*s_col[4*d4+1]+rv.z*s_col[4*d4+2]+rv.w*s_col[4*d4+3];
      }
      vn[it]=a;
      vbuf[(size_t)(b*T_+t0+c)*D_ + h*64 + l] = a;
      wkop[base + c*64 + l] = DEc[c]*o;
    }
    __syncthreads();   // all reads of WCD done
    // VNS (= v_new * DW) over WCD
    #pragma unroll
    for(int it=0;it<4;++it){
      int c = 4*w+it;
      WCD[c*64+l] = vn[it]*DW[c];
    }
    __syncthreads();

    // S update: Snew[r][l] = elast*S[r][l] + sum_c wk[c][r]*VNS[c][l]
    float elast = DEc[63];
    float vns_col[64];
    #pragma unroll
    for(int c=0;c<64;++c) vns_col[c]=WCD[c*64+l];
    float4 pvv = *(const float4*)(PREV + 4*w);
    float sn[4];
    sn[0] = elast*S[(4*w+0)*64+l] + pvv.x*vns_col[0];
    sn[1] = elast*S[(4*w+1)*64+l] + pvv.y*vns_col[0];
    sn[2] = elast*S[(4*w+2)*64+l] + pvv.z*vns_col[0];
    sn[3] = elast*S[(4*w+3)*64+l] + pvv.w*vns_col[0];
    #pragma unroll 9
    for(int c=1;c<64;++c){
      float4 rseg = *(const float4*)(&RK[(c-1)*64 + 4*w]);  // wk[c] = rk[c-1]
      float vc = vns_col[c];
      sn[0] += rseg.x*vc;
      sn[1] += rseg.y*vc;
      sn[2] += rseg.z*vc;
      sn[3] += rseg.w*vc;
    }
    // Frobenius norm clip
    float p=0.f;
    #pragma unroll
    for(int it=0;it<4;++it) p += sn[it]*sn[it];
    p = wave_sum(p);
    if(l==0) P[w]=p;
    __syncthreads();
    float4 q0 = *(const float4*)(P);
    float4 q1 = *(const float4*)(P+4);
    float4 q2 = *(const float4*)(P+8);
    float4 q3 = *(const float4*)(P+12);
    float nrm = sqrtf(q0.x+q0.y+q0.z+q0.w + q1.x+q1.y+q1.z+q1.w
                    + q2.x+q2.y+q2.z+q2.w + q3.x+q3.y+q3.z+q3.w);
    float scale = fminf(nrm,100.f)/fmaxf(nrm,1e-6f);
    #pragma unroll
    for(int it=0;it<4;++it){
      int r = 4*w+it;
      S[r*64+l] = sn[it]*scale;
    }
    if(tid<64) PREV[tid] = RK[63*64+tid];
    __syncthreads();
  }
}

// ---------------------------------------------------------------------------
// K5: o = gate*(opart + intra @ v_new); intra recomputed from rk/wk; o in-place
// ---------------------------------------------------------------------------
__global__ __launch_bounds__(256) void k_o(const float* __restrict__ x,
    const float* __restrict__ invn, const float* __restrict__ cum_g,
    const float* __restrict__ wkop, const float* __restrict__ gate_g,
    float* __restrict__ vbuf){
  int bid = blockIdx.x; int n = bid&63, h=(bid>>6)&15, b=bid>>10;
  int t0 = n*C_;
  __shared__ float sm[8256];
  float* RK = sm;        // 64x64 rk chunk, later INT (intra)
  float* VN = sm+4096;   // 64x64 v_new chunk
  float* CU = sm+8192;   // 64
  float* INT = RK;
  int tid=threadIdx.x, w=tid>>6, l=tid&63;
  if(tid<64) CU[tid] = cum_g[(size_t)bid*64 + tid];
  #pragma unroll 1
  for(int it=0;it<16;++it){
    int idx = tid+256*it; int c=idx>>6, dd=idx&63;
    size_t rr = (size_t)(b*T_+t0+c);
    RK[c*64+dd] = x[rr*D_ + h*64 + dd] * invn[rr*H_ + h];
    VN[idx]     = vbuf[rr*D_ + h*64 + dd];
  }
  __syncthreads();
  // wk column j=l into regs (wk[l] = rk[t0+l-1])
  float wkj[64];
  {
    int tw = t0+l-1;
    if(tw>=0){
      size_t r2 = (size_t)(b*T_+tw);
      float iv = invn[r2*H_ + h];
      #pragma unroll
      for(int d4=0; d4<16; ++d4){
        float4 u = *(const float4*)(x + r2*D_ + h*64 + 4*d4);
        wkj[4*d4+0]=u.x*iv; wkj[4*d4+1]=u.y*iv;
        wkj[4*d4+2]=u.z*iv; wkj[4*d4+3]=u.w*iv;
      }
    } else {
      #pragma unroll
      for(int dd=0;dd<64;++dd) wkj[dd]=0.f;
    }
  }
  // intra[i][l] = (rk_i . wk_l) * L[i][l]; write over RK (lockstep-safe per row)
  #pragma unroll 1
  for(int it=0;it<16;++it){
    int i = w + 4*it;
    float ar = 0.f;
    #pragma unroll
    for(int d4=0; d4<16; ++d4){
      float4 r4 = *(const float4*)&RK[i*64 + 4*d4];
      ar += r4.x*wkj[4*d4] + r4.y*wkj[4*d4+1] + r4.z*wkj[4*d4+2] + r4.w*wkj[4*d4+3];
    }
    float val = (l<=i) ? (ar*expf(CU[i]-CU[l])) : 0.f;
    INT[i*64+l] = val;   // all lanes' reads of row i complete before this (lockstep)
  }
  __syncthreads();
  float vn_col[64];
  #pragma unroll
  for(int k=0;k<64;++k) vn_col[k] = VN[k*64+l];
  #pragma unroll 1
  for(int it=0;it<16;++it){
    int c = w+4*it;
    float acc = 0.f;
    #pragma unroll
    for(int d4=0; d4<16; ++d4){
      float4 i4 = *(const float4*)&INT[c*64 + 4*d4];
      acc += i4.x*vn_col[4*d4] + i4.y*vn_col[4*d4+1] + i4.z*vn_col[4*d4+2] + i4.w*vn_col[4*d4+3];
    }
    size_t rr = (size_t)(b*T_+t0+c);
    float g  = gate_g[rr*H_ + h];
    float op = wkop[(size_t)bid*4096 + c*64 + l];
    vbuf[rr*D_ + h*64 + l] = (op + acc)*g;
  }
}

// ---------------------------------------------------------------------------
extern "C" void kernel_launch(void* const* d_in, const int* in_sizes, int n_in,
                              void* d_out, int out_size, void* d_ws, size_t ws_size,
                              hipStream_t stream) {
  const float* x       = (const float*)d_in[0];
  const float* w_write = (const float*)d_in[1];
  const float* w_gate  = (const float*)d_in[2];
  const float* w_out   = (const float*)d_in[3];
  const float* w_beta  = (const float*)d_in[4];
  const float* w_alpha = (const float*)d_in[5];
  const float* dt_bias = (const float*)d_in[6];
  const float* A_log   = (const float*)d_in[7];
  float* outp = (float*)d_out;

  const size_t big   = (size_t)BT_*D_;   // 16,777,216 floats
  const size_t small = (size_t)BT_*H_;   //    262,144 floats
  const size_t need  = (2*big + 5*small)*sizeof(float);   // ~139.5 MB
  if(ws_size < need) return;   // diagnostic: wrong-answer instead of fault

  float* ws   = (float*)d_ws;
  float* vbuf = ws;              // v -> v_corr -> v_new -> o
  float* wkop = vbuf + big;      // wk_cd -> opart
  float* invn = wkop + big;
  float* gate = invn + small;
  float* beta = gate + small;
  float* dec  = beta + small;
  float* cum  = dec  + small;

  k_small<<<dim3(BT_), dim3(256), 0, stream>>>(x, w_gate, w_beta, w_alpha,
      dt_bias, A_log, invn, gate, beta, dec);
  k_gemm_bb<<<dim3(D_/BN, BT_/BM), dim3(256), 0, stream>>>(x, w_write, vbuf,
      BT_, D_, D_);
  k_chunk<<<dim3(B_*H_*N_), dim3(256), 0, stream>>>(x, invn, beta, dec,
      cum, vbuf, wkop);
  k_scan<<<dim3(B_*H_), dim3(1024), 0, stream>>>(x, invn, cum, vbuf, wkop);
  k_o<<<dim3(B_*H_*N_), dim3(256), 0, stream>>>(x, invn, cum, wkop, gate, vbuf);
  k_gemm_out<<<dim3(D_/BN, BT_/BM), dim3(256), 0, stream>>>(vbuf, w_out, x,
      outp, BT_, D_, D_);
}

// Round 2
// 2764.981 us; speedup vs baseline: 1.6281x; 1.4676x over previous
//
#include <hip/hip_runtime.h>
#include <stdint.h>

#define B_ 4
#define T_ 4096
#define D_ 1024
#define H_ 16
#define HD_ 64
#define C_ 64
#define N_ 64
#define BT_ (B_*T_)

typedef unsigned short u16;

__device__ __forceinline__ float wave_sum(float v){
  #pragma unroll
  for(int off=32; off>0; off>>=1) v += __shfl_down(v, off);
  return __shfl(v, 0);
}

// ---------------------------------------------------------------------------
// K1 v2: tiled skinny GEMM. Block = 16 rows, thread (row,h)=(tid>>4, tid&15).
//   K tiled by 64 (= one head segment). W tiles staged transposed [h][kk]
//   (pad 68 -> conflict-free b128 reads). ss for head h accumulated during
//   tile t==h from the same staged x values. No shuffles, no uncoalesced
//   global loads. Outputs at blockIdx*256+tid (fully coalesced).
// ---------------------------------------------------------------------------
#define KSR 16   // rows per block
__global__ __launch_bounds__(256) void k_small(const float* __restrict__ x,
    const float* __restrict__ wg, const float* __restrict__ wb, const float* __restrict__ wa,
    const float* __restrict__ dtb, const float* __restrict__ alog,
    float* __restrict__ invn, float* __restrict__ gate, float* __restrict__ beta,
    float* __restrict__ dec){
  __shared__ float Xs [KSR][68];
  __shared__ float Wgt[H_ ][68];
  __shared__ float Wbt[H_ ][68];
  __shared__ float Wat[H_ ][68];
  int tid = threadIdx.x;
  int r = tid>>4, h = tid&15;
  int row0 = blockIdx.x*KSR;

  // staging thread mapping
  int sr = tid>>4, sf = (tid&15);      // x: row sr, float4 slot sf
  int wk = tid>>2, wj = tid&3;         // W: k row wk, float4 col slot wj

  float dg=0.f, db=0.f, da=0.f, ss=0.f;

  // prefetch tile 0
  float4 px = *(const float4*)(x + (size_t)(row0+sr)*D_ + sf*4);
  float4 pg = *(const float4*)(wg + (size_t)wk*H_ + 4*wj);
  float4 pb = *(const float4*)(wb + (size_t)wk*H_ + 4*wj);
  float4 pa = *(const float4*)(wa + (size_t)wk*H_ + 4*wj);

  for(int t=0; t<16; ++t){
    __syncthreads();          // previous compute done reading LDS
    // write staged regs
    *(float4*)&Xs[sr][sf*4] = px;
    Wgt[4*wj+0][wk]=pg.x; Wgt[4*wj+1][wk]=pg.y; Wgt[4*wj+2][wk]=pg.z; Wgt[4*wj+3][wk]=pg.w;
    Wbt[4*wj+0][wk]=pb.x; Wbt[4*wj+1][wk]=pb.y; Wbt[4*wj+2][wk]=pb.z; Wbt[4*wj+3][wk]=pb.w;
    Wat[4*wj+0][wk]=pa.x; Wat[4*wj+1][wk]=pa.y; Wat[4*wj+2][wk]=pa.z; Wat[4*wj+3][wk]=pa.w;
    // issue next tile's loads (overlap with this tile's compute)
    if(t<15){
      int k0 = (t+1)*64;
      px = *(const float4*)(x + (size_t)(row0+sr)*D_ + k0 + sf*4);
      pg = *(const float4*)(wg + (size_t)(k0+wk)*H_ + 4*wj);
      pb = *(const float4*)(wb + (size_t)(k0+wk)*H_ + 4*wj);
      pa = *(const float4*)(wa + (size_t)(k0+wk)*H_ + 4*wj);
    }
    __syncthreads();
    #pragma unroll
    for(int q=0;q<16;++q){
      float4 xv = *(const float4*)&Xs[r][4*q];
      float4 g4 = *(const float4*)&Wgt[h][4*q];
      float4 b4 = *(const float4*)&Wbt[h][4*q];
      float4 a4 = *(const float4*)&Wat[h][4*q];
      dg += xv.x*g4.x + xv.y*g4.y + xv.z*g4.z + xv.w*g4.w;
      db += xv.x*b4.x + xv.y*b4.y + xv.z*b4.z + xv.w*b4.w;
      da += xv.x*a4.x + xv.y*a4.y + xv.z*a4.z + xv.w*a4.w;
      if(t==h) ss += xv.x*xv.x + xv.y*xv.y + xv.z*xv.z + xv.w*xv.w;
    }
  }

  int o = row0*H_ + tid;     // == (row0+r)*H_ + h
  invn[o] = 1.f/fmaxf(sqrtf(ss),1e-12f);
  gate[o] = 1.f/(1.f+expf(-dg));
  beta[o] = 1.f/(1.f+expf(-db));
  float z = da + dtb[h];
  float sp = (z>20.f)? z : log1pf(expf(z));
  dec[o] = -expf(alog[h])*sp;
}

// ---------------------------------------------------------------------------
// K2: C(f32) = A(f32) @ B(f32), 128x128 tile, BK=8, 8x8/thread
// ---------------------------------------------------------------------------
#define BM 128
#define BN 128
#define BK 8
__global__ __launch_bounds__(256) void k_gemm_bb(const float* __restrict__ A,
    const float* __restrict__ Bw, float* __restrict__ Cc, int M, int Nn, int K){
  __shared__ float As[BK][BM];
  __shared__ float Bs[BK][BN];
  int tid = threadIdx.x;
  int tx = tid & 15, ty = tid >> 4;
  int m0 = blockIdx.y*BM, n0 = blockIdx.x*BN;
  int arow = tid>>1, ak = (tid&1)*4;
  int bk = tid>>5, bcol = (tid&31)*4;
  float acc[8][8] = {};
  for(int k0=0;k0<K;k0+=BK){
    float4 ua = *(const float4*)(A  + (size_t)(m0+arow)*K + k0+ak);
    float4 ub = *(const float4*)(Bw + (size_t)(k0+bk)*Nn + n0+bcol);
    __syncthreads();
    As[ak+0][arow]=ua.x; As[ak+1][arow]=ua.y;
    As[ak+2][arow]=ua.z; As[ak+3][arow]=ua.w;
    Bs[bk][bcol+0]=ub.x; Bs[bk][bcol+1]=ub.y;
    Bs[bk][bcol+2]=ub.z; Bs[bk][bcol+3]=ub.w;
    __syncthreads();
    #pragma unroll
    for(int kk=0;kk<BK;++kk){
      float a[8], b[8];
      *(float4*)&a[0] = *(const float4*)&As[kk][ty*8];
      *(float4*)&a[4] = *(const float4*)&As[kk][ty*8+4];
      *(float4*)&b[0] = *(const float4*)&Bs[kk][tx*8];
      *(float4*)&b[4] = *(const float4*)&Bs[kk][tx*8+4];
      #pragma unroll
      for(int i=0;i<8;++i)
        #pragma unroll
        for(int j=0;j<8;++j) acc[i][j] += a[i]*b[j];
    }
  }
  for(int i=0;i<8;++i){
    float4 v0 = {acc[i][0],acc[i][1],acc[i][2],acc[i][3]};
    float4 v1 = {acc[i][4],acc[i][5],acc[i][6],acc[i][7]};
    *(float4*)(Cc + (size_t)(m0+ty*8+i)*Nn + n0+tx*8)   = v0;
    *(float4*)(Cc + (size_t)(m0+ty*8+i)*Nn + n0+tx*8+4) = v1;
  }
}

// ---------------------------------------------------------------------------
// K6: Out(f32) = resid(f32) + A(f32) @ B(f32)
// ---------------------------------------------------------------------------
__global__ __launch_bounds__(256) void k_gemm_out(const float* __restrict__ A,
    const float* __restrict__ Bw, const float* __restrict__ resid, float* __restrict__ Outp,
    int M, int Nn, int K){
  __shared__ float As[BK][BM];
  __shared__ float Bs[BK][BN];
  int tid = threadIdx.x;
  int tx = tid & 15, ty = tid >> 4;
  int m0 = blockIdx.y*BM, n0 = blockIdx.x*BN;
  int arow = tid>>1, ak = (tid&1)*4;
  int bk = tid>>5, bcol = (tid&31)*4;
  float acc[8][8] = {};
  for(int k0=0;k0<K;k0+=BK){
    float4 fa = *(const float4*)(A + (size_t)(m0+arow)*K + k0+ak);
    float4 ub = *(const float4*)(Bw + (size_t)(k0+bk)*Nn + n0+bcol);
    __syncthreads();
    As[ak+0][arow]=fa.x; As[ak+1][arow]=fa.y; As[ak+2][arow]=fa.z; As[ak+3][arow]=fa.w;
    Bs[bk][bcol+0]=ub.x; Bs[bk][bcol+1]=ub.y;
    Bs[bk][bcol+2]=ub.z; Bs[bk][bcol+3]=ub.w;
    __syncthreads();
    #pragma unroll
    for(int kk=0;kk<BK;++kk){
      float a[8], b[8];
      *(float4*)&a[0] = *(const float4*)&As[kk][ty*8];
      *(float4*)&a[4] = *(const float4*)&As[kk][ty*8+4];
      *(float4*)&b[0] = *(const float4*)&Bs[kk][tx*8];
      *(float4*)&b[4] = *(const float4*)&Bs[kk][tx*8+4];
      #pragma unroll
      for(int i=0;i<8;++i)
        #pragma unroll
        for(int j=0;j<8;++j) acc[i][j] += a[i]*b[j];
    }
  }
  for(int i=0;i<8;++i){
    size_t ro = (size_t)(m0+ty*8+i)*Nn + n0+tx*8;
    float4 r0 = *(const float4*)(resid + ro);
    float4 r1 = *(const float4*)(resid + ro + 4);
    float4 s0, s1;
    s0.x=acc[i][0]+r0.x; s0.y=acc[i][1]+r0.y;
    s0.z=acc[i][2]+r0.z; s0.w=acc[i][3]+r0.w;
    s1.x=acc[i][4]+r1.x; s1.y=acc[i][5]+r1.y;
    s1.z=acc[i][6]+r1.z; s1.w=acc[i][7]+r1.w;
    *(float4*)(Outp + ro)     = s0;
    *(float4*)(Outp + ro + 4) = s1;
  }
}

// ---------------------------------------------------------------------------
// K3: per-chunk: cum, KK, forward substitution -> v_corr (in-place in vbuf),
//     wk_cd -> wkop
// ---------------------------------------------------------------------------
__global__ __launch_bounds__(256) void k_chunk(const float* __restrict__ x,
    const float* __restrict__ invn, const float* __restrict__ beta_g,
    const float* __restrict__ dec_g, float* __restrict__ cum_g,
    float* __restrict__ vbuf, float* __restrict__ wkop){
  int bid = blockIdx.x;                  // b*H*N + h*N + n
  int n = bid & 63; int h = (bid>>6) & 15; int b = bid>>10;
  int t0 = n*C_;
  __shared__ float sm[12608];
  float* WK = sm;            // 64*65 (padded), aliased by XV later
  float* KK = sm+4160;       // 64*64
  float* XW = sm+8256;       // 64*64
  float* BS = sm+12352;      // 64
  float* CU = sm+12416;      // 64
  float* DE = sm+12480;      // 64
  float* GS = sm+12544;      // 64
  float* XV = WK;            // 4096 over WK region (stride 64)
  int tid = threadIdx.x, w = tid>>6, l = tid&63;
  // A: stage shifted normalized keys + beta + decay
  #pragma unroll
  for(int it=0; it<16; ++it){
    int idx = tid + 256*it; int c = idx>>6, dd = idx&63;
    int tw = t0+c-1;
    float wv = 0.f;
    if(tw>=0){
      size_t rr = (size_t)(b*T_+tw);
      wv = x[rr*D_ + h*64 + dd] * invn[rr*H_ + h];
    }
    WK[c*65+dd] = wv;
  }
  if(tid<64){
    size_t rr = (size_t)(b*T_+t0+tid);
    BS[tid] = beta_g[rr*H_+h];
    GS[tid] = dec_g[rr*H_+h];
  }
  __syncthreads();
  // B: inclusive cumsum of decay (wave 0)
  if(w==0){
    float xg = GS[l];
    #pragma unroll
    for(int off=1; off<64; off<<=1){
      float y = __shfl_up(xg, off);
      if(l>=off) xg += y;
    }
    CU[l]=xg; DE[l]=expf(xg);
    cum_g[(size_t)bid*64 + l] = xg;
  }
  __syncthreads();
  // C: KK[i][j] = beta_i * (wk_i . wk_j) * L[i][j], strict lower
  float wkj[64];
  #pragma unroll
  for(int dd=0; dd<64; ++dd) wkj[dd] = WK[l*65+dd];
  #pragma unroll 1
  for(int it=0; it<16; ++it){
    int i = w + 4*it;
    float aw=0.f;
    #pragma unroll
    for(int dd=0; dd<64; ++dd) aw += WK[i*65+dd]*wkj[dd];
    KK[i*64+l] = (l<i) ? (BS[i]*aw*expf(CU[i]-CU[l])) : 0.f;
  }
  __syncthreads();
  // D: capture rhs into regs, then write XV (over WK), XW
  float rv[16], rw[16];
  #pragma unroll
  for(int it=0; it<16; ++it){
    int i = w + 4*it;
    rw[it] = WK[i*65+l]*BS[i]*DE[i];
    rv[it] = vbuf[(size_t)(b*T_+t0+i)*D_ + h*64 + l]*BS[i];
  }
  __syncthreads();
  #pragma unroll
  for(int it=0; it<16; ++it){
    int i = w + 4*it;
    XV[i*64+l] = rv[it];
    XW[i*64+l] = rw[it];
  }
  __syncthreads();
  // E: forward substitution (I + strict_lower(KK)) X = rhs (waves 0,1)
  if(w<2){
    float* Xc = (w==0) ? XV : XW;
    for(int i=1;i<64;++i){
      float acc = Xc[i*64+l];
      for(int k=0;k<i;++k) acc -= KK[i*64+k]*Xc[k*64+l];
      Xc[i*64+l] = acc;
    }
  }
  __syncthreads();
  // F: write v_corr (in place), wk_cd
  #pragma unroll
  for(int it=0; it<16; ++it){
    int i = w + 4*it;
    vbuf[(size_t)(b*T_+t0+i)*D_ + h*64 + l] = XV[i*64+l];
    wkop[(size_t)bid*4096 + i*64 + l]       = XW[i*64+l];
  }
}

// ---------------------------------------------------------------------------
// K4 v3: sequential scan per (b,h), 1024 threads (16 waves -> 4 waves/SIMD).
// ---------------------------------------------------------------------------
__global__ __launch_bounds__(1024, 4) void k_scan(const float* __restrict__ x,
    const float* __restrict__ invn_g, const float* __restrict__ cum_g,
    float* __restrict__ vbuf, float* __restrict__ wkop){
  int bh = blockIdx.x;  // b*H + h
  int b = bh>>4, h = bh&15;
  __shared__ float sm[12496];
  float* S   = sm;          // 64x64 state
  float* WCD = sm+4096;     // wkcd chunk; later VNS (= v_new * DW)
  float* RK  = sm+8192;     // rk chunk (pre-scaled by invn)
  float* DW  = sm+12288;    // 64: exp(last-cum)
  float* DEc = sm+12352;    // 64: exp(cum)
  float* PREV= sm+12416;    // 64: prev chunk's last rk row (scaled)
  float* P   = sm+12480;    // 16
  int tid = threadIdx.x, w = tid>>6, l = tid&63;

  #pragma unroll
  for(int it=0;it<4;++it) S[tid+1024*it]=0.f;
  if(tid<64) PREV[tid]=0.f;

  // prologue: prefetch chunk 0 into regs
  float4 pW, pR;
  float pV[4], pC=0.f, pLast=0.f, pIv=0.f;
  {
    size_t base0 = (size_t)bh*N_*4096;
    pW = *(const float4*)(wkop + base0 + (size_t)tid*4);
    int c = tid>>4, c4 = (tid&15)*4;
    pR = *(const float4*)(x + (size_t)(b*T_+c)*D_ + h*64 + c4);
    pIv = invn_g[(size_t)(b*T_+c)*H_ + h];
    #pragma unroll
    for(int it=0;it<4;++it)
      pV[it] = vbuf[(size_t)(b*T_+4*w+it)*D_ + h*64 + l];
    if(tid<64){
      pC    = cum_g[(size_t)bh*N_*64 + tid];
      pLast = cum_g[(size_t)bh*N_*64 + 63];
    }
  }
  __syncthreads();

  for(int n=0;n<N_;++n){
    int t0 = n*C_;
    size_t base = ((size_t)bh*N_ + n)*4096;
    // stage: WCD, RK (scaled), DW/DEc — single barrier
    *(float4*)(WCD + (size_t)tid*4) = pW;
    {
      float4 r = pR;
      r.x*=pIv; r.y*=pIv; r.z*=pIv; r.w*=pIv;
      *(float4*)(RK + (size_t)tid*4) = r;
    }
    if(tid<64){
      DW[tid]  = expf(pLast - pC);
      DEc[tid] = expf(pC);
    }
    __syncthreads();

    // consume pV into accumulators, then prefetch chunk n+1
    float vn[4];
    #pragma unroll
    for(int it=0;it<4;++it) vn[it]=pV[it];
    if(n+1 < N_){
      int t1 = t0 + C_;
      size_t base1 = base + 4096;
      pW = *(const float4*)(wkop + base1 + (size_t)tid*4);
      int c = tid>>4, c4=(tid&15)*4;
      pR = *(const float4*)(x + (size_t)(b*T_+t1+c)*D_ + h*64 + c4);
      pIv = invn_g[(size_t)(b*T_+t1+c)*H_ + h];
      #pragma unroll
      for(int it=0;it<4;++it)
        pV[it] = vbuf[(size_t)(b*T_+t1+4*w+it)*D_ + h*64 + l];
      if(tid<64){
        pC    = cum_g[((size_t)bh*N_+n+1)*64 + tid];
        pLast = cum_g[((size_t)bh*N_+n+1)*64 + 63];
      }
    }

    // s_col = column l of S_pre
    float s_col[64];
    #pragma unroll
    for(int k=0;k<64;++k) s_col[k]=S[k*64+l];

    // v_new = v_corr - wkcd @ S_pre ; opart = exp(cum)*(rk @ S_pre)
    #pragma unroll
    for(int it=0;it<4;++it){
      int c = 4*w+it;
      float a = vn[it], o = 0.f;
      #pragma unroll
      for(int d4=0;d4<16;++d4){
        float4 wv = *(const float4*)&WCD[c*64+4*d4];
        float4 rv = *(const float4*)&RK [c*64+4*d4];
        a -= wv.x*s_col[4*d4]+wv.y*s_col[4*d4+1]+wv.z*s_col[4*d4+2]+wv.w*s_col[4*d4+3];
        o += rv.x*s_col[4*d4]+rv.y*s_col[4*d4+1]+rv.z*s_col[4*d4+2]+rv.w*s_col[4*d4+3];
      }
      vn[it]=a;
      vbuf[(size_t)(b*T_+t0+c)*D_ + h*64 + l] = a;
      wkop[base + c*64 + l] = DEc[c]*o;
    }
    __syncthreads();   // all reads of WCD done
    // VNS (= v_new * DW) over WCD
    #pragma unroll
    for(int it=0;it<4;++it){
      int c = 4*w+it;
      WCD[c*64+l] = vn[it]*DW[c];
    }
    __syncthreads();

    // S update: Snew[r][l] = elast*S[r][l] + sum_c wk[c][r]*VNS[c][l]
    float elast = DEc[63];
    float vns_col[64];
    #pragma unroll
    for(int c=0;c<64;++c) vns_col[c]=WCD[c*64+l];
    float4 pvv = *(const float4*)(PREV + 4*w);
    float sn[4];
    sn[0] = elast*S[(4*w+0)*64+l] + pvv.x*vns_col[0];
    sn[1] = elast*S[(4*w+1)*64+l] + pvv.y*vns_col[0];
    sn[2] = elast*S[(4*w+2)*64+l] + pvv.z*vns_col[0];
    sn[3] = elast*S[(4*w+3)*64+l] + pvv.w*vns_col[0];
    #pragma unroll 9
    for(int c=1;c<64;++c){
      float4 rseg = *(const float4*)(&RK[(c-1)*64 + 4*w]);  // wk[c] = rk[c-1]
      float vc = vns_col[c];
      sn[0] += rseg.x*vc;
      sn[1] += rseg.y*vc;
      sn[2] += rseg.z*vc;
      sn[3] += rseg.w*vc;
    }
    // Frobenius norm clip
    float p=0.f;
    #pragma unroll
    for(int it=0;it<4;++it) p += sn[it]*sn[it];
    p = wave_sum(p);
    if(l==0) P[w]=p;
    __syncthreads();
    float4 q0 = *(const float4*)(P);
    float4 q1 = *(const float4*)(P+4);
    float4 q2 = *(const float4*)(P+8);
    float4 q3 = *(const float4*)(P+12);
    float nrm = sqrtf(q0.x+q0.y+q0.z+q0.w + q1.x+q1.y+q1.z+q1.w
                    + q2.x+q2.y+q2.z+q2.w + q3.x+q3.y+q3.z+q3.w);
    float scale = fminf(nrm,100.f)/fmaxf(nrm,1e-6f);
    #pragma unroll
    for(int it=0;it<4;++it){
      int r = 4*w+it;
      S[r*64+l] = sn[it]*scale;
    }
    if(tid<64) PREV[tid] = RK[63*64+tid];
    __syncthreads();
  }
}

// ---------------------------------------------------------------------------
// K5: o = gate*(opart + intra @ v_new); intra recomputed from rk/wk; o in-place
// ---------------------------------------------------------------------------
__global__ __launch_bounds__(256) void k_o(const float* __restrict__ x,
    const float* __restrict__ invn, const float* __restrict__ cum_g,
    const float* __restrict__ wkop, const float* __restrict__ gate_g,
    float* __restrict__ vbuf){
  int bid = blockIdx.x; int n = bid&63, h=(bid>>6)&15, b=bid>>10;
  int t0 = n*C_;
  __shared__ float sm[8256];
  float* RK = sm;        // 64x64 rk chunk, later INT (intra)
  float* VN = sm+4096;   // 64x64 v_new chunk
  float* CU = sm+8192;   // 64
  float* INT = RK;
  int tid=threadIdx.x, w=tid>>6, l=tid&63;
  if(tid<64) CU[tid] = cum_g[(size_t)bid*64 + tid];
  #pragma unroll 1
  for(int it=0;it<16;++it){
    int idx = tid+256*it; int c=idx>>6, dd=idx&63;
    size_t rr = (size_t)(b*T_+t0+c);
    RK[c*64+dd] = x[rr*D_ + h*64 + dd] * invn[rr*H_ + h];
    VN[idx]     = vbuf[rr*D_ + h*64 + dd];
  }
  __syncthreads();
  // wk column j=l into regs (wk[l] = rk[t0+l-1])
  float wkj[64];
  {
    int tw = t0+l-1;
    if(tw>=0){
      size_t r2 = (size_t)(b*T_+tw);
      float iv = invn[r2*H_ + h];
      #pragma unroll
      for(int d4=0; d4<16; ++d4){
        float4 u = *(const float4*)(x + r2*D_ + h*64 + 4*d4);
        wkj[4*d4+0]=u.x*iv; wkj[4*d4+1]=u.y*iv;
        wkj[4*d4+2]=u.z*iv; wkj[4*d4+3]=u.w*iv;
      }
    } else {
      #pragma unroll
      for(int dd=0;dd<64;++dd) wkj[dd]=0.f;
    }
  }
  // intra[i][l] = (rk_i . wk_l) * L[i][l]; write over RK (lockstep-safe per row)
  #pragma unroll 1
  for(int it=0;it<16;++it){
    int i = w + 4*it;
    float ar = 0.f;
    #pragma unroll
    for(int d4=0; d4<16; ++d4){
      float4 r4 = *(const float4*)&RK[i*64 + 4*d4];
      ar += r4.x*wkj[4*d4] + r4.y*wkj[4*d4+1] + r4.z*wkj[4*d4+2] + r4.w*wkj[4*d4+3];
    }
    float val = (l<=i) ? (ar*expf(CU[i]-CU[l])) : 0.f;
    INT[i*64+l] = val;   // all lanes' reads of row i complete before this (lockstep)
  }
  __syncthreads();
  float vn_col[64];
  #pragma unroll
  for(int k=0;k<64;++k) vn_col[k] = VN[k*64+l];
  #pragma unroll 1
  for(int it=0;it<16;++it){
    int c = w+4*it;
    float acc = 0.f;
    #pragma unroll
    for(int d4=0; d4<16; ++d4){
      float4 i4 = *(const float4*)&INT[c*64 + 4*d4];
      acc += i4.x*vn_col[4*d4] + i4.y*vn_col[4*d4+1] + i4.z*vn_col[4*d4+2] + i4.w*vn_col[4*d4+3];
    }
    size_t rr = (size_t)(b*T_+t0+c);
    float g  = gate_g[rr*H_ + h];
    float op = wkop[(size_t)bid*4096 + c*64 + l];
    vbuf[rr*D_ + h*64 + l] = (op + acc)*g;
  }
}

// ---------------------------------------------------------------------------
extern "C" void kernel_launch(void* const* d_in, const int* in_sizes, int n_in,
                              void* d_out, int out_size, void* d_ws, size_t ws_size,
                              hipStream_t stream) {
  const float* x       = (const float*)d_in[0];
  const float* w_write = (const float*)d_in[1];
  const float* w_gate  = (const float*)d_in[2];
  const float* w_out   = (const float*)d_in[3];
  const float* w_beta  = (const float*)d_in[4];
  const float* w_alpha = (const float*)d_in[5];
  const float* dt_bias = (const float*)d_in[6];
  const float* A_log   = (const float*)d_in[7];
  float* outp = (float*)d_out;

  const size_t big   = (size_t)BT_*D_;   // 16,777,216 floats
  const size_t small = (size_t)BT_*H_;   //    262,144 floats
  const size_t need  = (2*big + 5*small)*sizeof(float);   // ~139.5 MB
  if(ws_size < need) return;   // diagnostic: wrong-answer instead of fault

  float* ws   = (float*)d_ws;
  float* vbuf = ws;              // v -> v_corr -> v_new -> o
  float* wkop = vbuf + big;      // wk_cd -> opart
  float* invn = wkop + big;
  float* gate = invn + small;
  float* beta = gate + small;
  float* dec  = beta + small;
  float* cum  = dec  + small;

  k_small<<<dim3(BT_/KSR), dim3(256), 0, stream>>>(x, w_gate, w_beta, w_alpha,
      dt_bias, A_log, invn, gate, beta, dec);
  k_gemm_bb<<<dim3(D_/BN, BT_/BM), dim3(256), 0, stream>>>(x, w_write, vbuf,
      BT_, D_, D_);
  k_chunk<<<dim3(B_*H_*N_), dim3(256), 0, stream>>>(x, invn, beta, dec,
      cum, vbuf, wkop);
  k_scan<<<dim3(B_*H_), dim3(1024), 0, stream>>>(x, invn, cum, vbuf, wkop);
  k_o<<<dim3(B_*H_*N_), dim3(256), 0, stream>>>(x, invn, cum, wkop, gate, vbuf);
  k_gemm_out<<<dim3(D_/BN, BT_/BM), dim3(256), 0, stream>>>(vbuf, w_out, x,
      outp, BT_, D_, D_);
}

// Round 4
// 1833.220 us; speedup vs baseline: 2.4556x; 1.5083x over previous
//
#include <hip/hip_runtime.h>
#include <stdint.h>

#define B_ 4
#define T_ 4096
#define D_ 1024
#define H_ 16
#define HD_ 64
#define C_ 64
#define N_ 64
#define BT_ (B_*T_)

typedef unsigned short u16;

__device__ __forceinline__ float wave_sum(float v){
  #pragma unroll
  for(int off=32; off>0; off>>=1) v += __shfl_down(v, off);
  return __shfl(v, 0);
}

// ---------------------------------------------------------------------------
// K1 v2: tiled skinny GEMM (16 rows/block, 256 thr).
// ---------------------------------------------------------------------------
#define KSR 16   // rows per block
__global__ __launch_bounds__(256) void k_small(const float* __restrict__ x,
    const float* __restrict__ wg, const float* __restrict__ wb, const float* __restrict__ wa,
    const float* __restrict__ dtb, const float* __restrict__ alog,
    float* __restrict__ invn, float* __restrict__ gate, float* __restrict__ beta,
    float* __restrict__ dec){
  __shared__ float Xs [KSR][68];
  __shared__ float Wgt[H_ ][68];
  __shared__ float Wbt[H_ ][68];
  __shared__ float Wat[H_ ][68];
  int tid = threadIdx.x;
  int r = tid>>4, h = tid&15;
  int row0 = blockIdx.x*KSR;

  int sr = tid>>4, sf = (tid&15);      // x: row sr, float4 slot sf
  int wk = tid>>2, wj = tid&3;         // W: k row wk, float4 col slot wj

  float dg=0.f, db=0.f, da=0.f, ss=0.f;

  float4 px = *(const float4*)(x + (size_t)(row0+sr)*D_ + sf*4);
  float4 pg = *(const float4*)(wg + (size_t)wk*H_ + 4*wj);
  float4 pb = *(const float4*)(wb + (size_t)wk*H_ + 4*wj);
  float4 pa = *(const float4*)(wa + (size_t)wk*H_ + 4*wj);

  for(int t=0; t<16; ++t){
    __syncthreads();
    *(float4*)&Xs[sr][sf*4] = px;
    Wgt[4*wj+0][wk]=pg.x; Wgt[4*wj+1][wk]=pg.y; Wgt[4*wj+2][wk]=pg.z; Wgt[4*wj+3][wk]=pg.w;
    Wbt[4*wj+0][wk]=pb.x; Wbt[4*wj+1][wk]=pb.y; Wbt[4*wj+2][wk]=pb.z; Wbt[4*wj+3][wk]=pb.w;
    Wat[4*wj+0][wk]=pa.x; Wat[4*wj+1][wk]=pa.y; Wat[4*wj+2][wk]=pa.z; Wat[4*wj+3][wk]=pa.w;
    if(t<15){
      int k0 = (t+1)*64;
      px = *(const float4*)(x + (size_t)(row0+sr)*D_ + k0 + sf*4);
      pg = *(const float4*)(wg + (size_t)(k0+wk)*H_ + 4*wj);
      pb = *(const float4*)(wb + (size_t)(k0+wk)*H_ + 4*wj);
      pa = *(const float4*)(wa + (size_t)(k0+wk)*H_ + 4*wj);
    }
    __syncthreads();
    #pragma unroll
    for(int q=0;q<16;++q){
      float4 xv = *(const float4*)&Xs[r][4*q];
      float4 g4 = *(const float4*)&Wgt[h][4*q];
      float4 b4 = *(const float4*)&Wbt[h][4*q];
      float4 a4 = *(const float4*)&Wat[h][4*q];
      dg += xv.x*g4.x + xv.y*g4.y + xv.z*g4.z + xv.w*g4.w;
      db += xv.x*b4.x + xv.y*b4.y + xv.z*b4.z + xv.w*b4.w;
      da += xv.x*a4.x + xv.y*a4.y + xv.z*a4.z + xv.w*a4.w;
      if(t==h) ss += xv.x*xv.x + xv.y*xv.y + xv.z*xv.z + xv.w*xv.w;
    }
  }

  int o = row0*H_ + tid;
  invn[o] = 1.f/fmaxf(sqrtf(ss),1e-12f);
  gate[o] = 1.f/(1.f+expf(-dg));
  beta[o] = 1.f/(1.f+expf(-db));
  float z = da + dtb[h];
  float sp = (z>20.f)? z : log1pf(expf(z));
  dec[o] = -expf(alog[h])*sp;
}

// ---------------------------------------------------------------------------
// K2: C(f32) = A(f32) @ B(f32), 128x128 tile, BK=8, 8x8/thread
// ---------------------------------------------------------------------------
#define BM 128
#define BN 128
#define BK 8
__global__ __launch_bounds__(256) void k_gemm_bb(const float* __restrict__ A,
    const float* __restrict__ Bw, float* __restrict__ Cc, int M, int Nn, int K){
  __shared__ float As[BK][BM];
  __shared__ float Bs[BK][BN];
  int tid = threadIdx.x;
  int tx = tid & 15, ty = tid >> 4;
  int m0 = blockIdx.y*BM, n0 = blockIdx.x*BN;
  int arow = tid>>1, ak = (tid&1)*4;
  int bk = tid>>5, bcol = (tid&31)*4;
  float acc[8][8] = {};
  for(int k0=0;k0<K;k0+=BK){
    float4 ua = *(const float4*)(A  + (size_t)(m0+arow)*K + k0+ak);
    float4 ub = *(const float4*)(Bw + (size_t)(k0+bk)*Nn + n0+bcol);
    __syncthreads();
    As[ak+0][arow]=ua.x; As[ak+1][arow]=ua.y;
    As[ak+2][arow]=ua.z; As[ak+3][arow]=ua.w;
    Bs[bk][bcol+0]=ub.x; Bs[bk][bcol+1]=ub.y;
    Bs[bk][bcol+2]=ub.z; Bs[bk][bcol+3]=ub.w;
    __syncthreads();
    #pragma unroll
    for(int kk=0;kk<BK;++kk){
      float a[8], b[8];
      *(float4*)&a[0] = *(const float4*)&As[kk][ty*8];
      *(float4*)&a[4] = *(const float4*)&As[kk][ty*8+4];
      *(float4*)&b[0] = *(const float4*)&Bs[kk][tx*8];
      *(float4*)&b[4] = *(const float4*)&Bs[kk][tx*8+4];
      #pragma unroll
      for(int i=0;i<8;++i)
        #pragma unroll
        for(int j=0;j<8;++j) acc[i][j] += a[i]*b[j];
    }
  }
  for(int i=0;i<8;++i){
    float4 v0 = {acc[i][0],acc[i][1],acc[i][2],acc[i][3]};
    float4 v1 = {acc[i][4],acc[i][5],acc[i][6],acc[i][7]};
    *(float4*)(Cc + (size_t)(m0+ty*8+i)*Nn + n0+tx*8)   = v0;
    *(float4*)(Cc + (size_t)(m0+ty*8+i)*Nn + n0+tx*8+4) = v1;
  }
}

// ---------------------------------------------------------------------------
// K6: Out(f32) = resid(f32) + A(f32) @ B(f32)
// ---------------------------------------------------------------------------
__global__ __launch_bounds__(256) void k_gemm_out(const float* __restrict__ A,
    const float* __restrict__ Bw, const float* __restrict__ resid, float* __restrict__ Outp,
    int M, int Nn, int K){
  __shared__ float As[BK][BM];
  __shared__ float Bs[BK][BN];
  int tid = threadIdx.x;
  int tx = tid & 15, ty = tid >> 4;
  int m0 = blockIdx.y*BM, n0 = blockIdx.x*BN;
  int arow = tid>>1, ak = (tid&1)*4;
  int bk = tid>>5, bcol = (tid&31)*4;
  float acc[8][8] = {};
  for(int k0=0;k0<K;k0+=BK){
    float4 fa = *(const float4*)(A + (size_t)(m0+arow)*K + k0+ak);
    float4 ub = *(const float4*)(Bw + (size_t)(k0+bk)*Nn + n0+bcol);
    __syncthreads();
    As[ak+0][arow]=fa.x; As[ak+1][arow]=fa.y; As[ak+2][arow]=fa.z; As[ak+3][arow]=fa.w;
    Bs[bk][bcol+0]=ub.x; Bs[bk][bcol+1]=ub.y;
    Bs[bk][bcol+2]=ub.z; Bs[bk][bcol+3]=ub.w;
    __syncthreads();
    #pragma unroll
    for(int kk=0;kk<BK;++kk){
      float a[8], b[8];
      *(float4*)&a[0] = *(const float4*)&As[kk][ty*8];
      *(float4*)&a[4] = *(const float4*)&As[kk][ty*8+4];
      *(float4*)&b[0] = *(const float4*)&Bs[kk][tx*8];
      *(float4*)&b[4] = *(const float4*)&Bs[kk][tx*8+4];
      #pragma unroll
      for(int i=0;i<8;++i)
        #pragma unroll
        for(int j=0;j<8;++j) acc[i][j] += a[i]*b[j];
    }
  }
  for(int i=0;i<8;++i){
    size_t ro = (size_t)(m0+ty*8+i)*Nn + n0+tx*8;
    float4 r0 = *(const float4*)(resid + ro);
    float4 r1 = *(const float4*)(resid + ro + 4);
    float4 s0, s1;
    s0.x=acc[i][0]+r0.x; s0.y=acc[i][1]+r0.y;
    s0.z=acc[i][2]+r0.z; s0.w=acc[i][3]+r0.w;
    s1.x=acc[i][4]+r1.x; s1.y=acc[i][5]+r1.y;
    s1.z=acc[i][6]+r1.z; s1.w=acc[i][7]+r1.w;
    *(float4*)(Outp + ro)     = s0;
    *(float4*)(Outp + ro + 4) = s1;
  }
}

// ---------------------------------------------------------------------------
// K3: per-chunk: cum, KK, forward substitution -> v_corr (in-place in vbuf),
//     wk_cd -> wkop. Also zeroes this chunk's psum/cnt team-sync slot.
// ---------------------------------------------------------------------------
__global__ __launch_bounds__(256) void k_chunk(const float* __restrict__ x,
    const float* __restrict__ invn, const float* __restrict__ beta_g,
    const float* __restrict__ dec_g, float* __restrict__ cum_g,
    float* __restrict__ vbuf, float* __restrict__ wkop,
    float* __restrict__ psum, int* __restrict__ cnt){
  int bid = blockIdx.x;                  // b*H*N + h*N + n  == bh*64 + n
  int n = bid & 63; int h = (bid>>6) & 15; int b = bid>>10;
  int t0 = n*C_;
  __shared__ float sm[12608];
  float* WK = sm;            // 64*65 (padded), aliased by XV later
  float* KK = sm+4160;       // 64*64
  float* XW = sm+8256;       // 64*64
  float* BS = sm+12352;      // 64
  float* CU = sm+12416;      // 64
  float* DE = sm+12480;      // 64
  float* GS = sm+12544;      // 64
  float* XV = WK;            // 4096 over WK region (stride 64)
  int tid = threadIdx.x, w = tid>>6, l = tid&63;
  if(tid==0){ psum[bid]=0.f; cnt[bid]=0; }   // reset team-sync slot for k_scan
  // A: stage shifted normalized keys + beta + decay
  #pragma unroll
  for(int it=0; it<16; ++it){
    int idx = tid + 256*it; int c = idx>>6, dd = idx&63;
    int tw = t0+c-1;
    float wv = 0.f;
    if(tw>=0){
      size_t rr = (size_t)(b*T_+tw);
      wv = x[rr*D_ + h*64 + dd] * invn[rr*H_ + h];
    }
    WK[c*65+dd] = wv;
  }
  if(tid<64){
    size_t rr = (size_t)(b*T_+t0+tid);
    BS[tid] = beta_g[rr*H_+h];
    GS[tid] = dec_g[rr*H_+h];
  }
  __syncthreads();
  // B: inclusive cumsum of decay (wave 0)
  if(w==0){
    float xg = GS[l];
    #pragma unroll
    for(int off=1; off<64; off<<=1){
      float y = __shfl_up(xg, off);
      if(l>=off) xg += y;
    }
    CU[l]=xg; DE[l]=expf(xg);
    cum_g[(size_t)bid*64 + l] = xg;
  }
  __syncthreads();
  // C: KK[i][j] = beta_i * (wk_i . wk_j) * L[i][j], strict lower
  float wkj[64];
  #pragma unroll
  for(int dd=0; dd<64; ++dd) wkj[dd] = WK[l*65+dd];
  #pragma unroll 1
  for(int it=0; it<16; ++it){
    int i = w + 4*it;
    float aw=0.f;
    #pragma unroll
    for(int dd=0; dd<64; ++dd) aw += WK[i*65+dd]*wkj[dd];
    KK[i*64+l] = (l<i) ? (BS[i]*aw*expf(CU[i]-CU[l])) : 0.f;
  }
  __syncthreads();
  // D: capture rhs into regs, then write XV (over WK), XW
  float rv[16], rw[16];
  #pragma unroll
  for(int it=0; it<16; ++it){
    int i = w + 4*it;
    rw[it] = WK[i*65+l]*BS[i]*DE[i];
    rv[it] = vbuf[(size_t)(b*T_+t0+i)*D_ + h*64 + l]*BS[i];
  }
  __syncthreads();
  #pragma unroll
  for(int it=0; it<16; ++it){
    int i = w + 4*it;
    XV[i*64+l] = rv[it];
    XW[i*64+l] = rw[it];
  }
  __syncthreads();
  // E: forward substitution (I + strict_lower(KK)) X = rhs (waves 0,1)
  if(w<2){
    float* Xc = (w==0) ? XV : XW;
    for(int i=1;i<64;++i){
      float acc = Xc[i*64+l];
      for(int k=0;k<i;++k) acc -= KK[i*64+k]*Xc[k*64+l];
      Xc[i*64+l] = acc;
    }
  }
  __syncthreads();
  // F: write v_corr (in place), wk_cd
  #pragma unroll
  for(int it=0; it<16; ++it){
    int i = w + 4*it;
    vbuf[(size_t)(b*T_+t0+i)*D_ + h*64 + l] = XV[i*64+l];
    wkop[(size_t)bid*4096 + i*64 + l]       = XW[i*64+l];
  }
}

// ---------------------------------------------------------------------------
// K4 v4b: column-split team scan, HANG-PROOF variant. 256 blocks = 64 (b,h)
//   chains x 4 col-groups of 16 columns -> all 256 CUs active. Cross-column
//   coupling (Frobenius clip) combined via device-scope atomics per
//   (bh,chunk); S kept UNSCALED in LDS, scale applied lazily next chunk.
//   The spin is BOUNDED (~1M iters): a sync failure degrades to a wrong
//   answer with diagnostics instead of a GPU hang.
//   Ordering proof: prefetch of chunk n+1 (post-B1) happens-before this
//   block's release-add of slot n (post-B3; __syncthreads drains vmcnt),
//   which happens-before any teammate passes its acquire-spin on slot n,
//   which happens-before the teammate overwrites chunk n+1 data.
// ---------------------------------------------------------------------------
__global__ __launch_bounds__(1024, 4) void k_scan(const float* __restrict__ x,
    const float* __restrict__ invn_g, const float* __restrict__ cum_g,
    float* __restrict__ vbuf, float* __restrict__ wkop,
    float* __restrict__ psum, int* __restrict__ cnt){
  int bh = blockIdx.x & 63, cg = blockIdx.x >> 6;
  int b = bh>>4, h = bh&15, col0 = cg*16;
  __shared__ float sm[15448];
  float* WCD = sm;           // [64][68] wkcd rows
  float* RK  = sm+4352;      // [64][68] rk rows (scaled by invn)
  float* WKT = sm+8704;      // [64][68] WKT[d][c] = wk[c][d] (col 0 = PREV)
  float* VNS = sm+13056;     // [16][68] VNS[col][c] = v_new*DW, transposed
  float* ST  = sm+14144;     // [16][68] ST[col][d] = S (UNSCALED U), transposed
  float* DW  = sm+15232;     // 64: exp(last-cum)
  float* DEc = sm+15296;     // 64: exp(cum)
  float* PREV= sm+15360;     // 64: prev chunk's last rk row
  float* P   = sm+15424;     // 16
  float* NRM = sm+15440;     // 1
  int tid = threadIdx.x, w = tid>>6, l = tid&63;
  int c = tid>>4, q4 = tid&15;     // row / float4-slot (stage)
  int col = tid&15;                // local column (compute)

  for(int i=tid;i<1088;i+=1024) ST[i]=0.f;
  if(tid<64) PREV[tid]=0.f;

  // prologue prefetch chunk 0
  float4 pW, pR; float pIv, pV, pC=0.f, pLast=0.f;
  {
    size_t base0 = (size_t)bh*N_*4096;
    pW = *(const float4*)(wkop + base0 + (size_t)tid*4);
    pR = *(const float4*)(x + (size_t)(b*T_+c)*D_ + h*64 + 4*q4);
    pIv = invn_g[(size_t)(b*T_+c)*H_ + h];
    pV  = vbuf[(size_t)(b*T_+c)*D_ + h*64 + col0+col];
    if(tid<64){
      pC    = cum_g[(size_t)bh*N_*64 + tid];
      pLast = cum_g[(size_t)bh*N_*64 + 63];
    }
  }
  __syncthreads();

  float scale = 1.f;
  for(int n=0;n<N_;++n){
    int t0 = n*C_;
    size_t base = ((size_t)bh*N_+n)*4096;
    // ---- stage (regions last read before prev chunk's final barrier) ----
    *(float4*)&WCD[c*68+4*q4] = pW;
    float4 rv4;
    rv4.x=pR.x*pIv; rv4.y=pR.y*pIv; rv4.z=pR.z*pIv; rv4.w=pR.w*pIv;
    *(float4*)&RK[c*68+4*q4] = rv4;
    if(c<63){
      WKT[(4*q4+0)*68 + c+1]=rv4.x;
      WKT[(4*q4+1)*68 + c+1]=rv4.y;
      WKT[(4*q4+2)*68 + c+1]=rv4.z;
      WKT[(4*q4+3)*68 + c+1]=rv4.w;
    }
    if(tid<64){
      WKT[tid*68+0] = PREV[tid];
      DW[tid]  = expf(pLast-pC);
      DEc[tid] = expf(pC);
    }
    // ---- bounded spin for previous chunk's team norm ----
    if(n>0 && tid==0){
      int slot = bh*N_ + n-1;
      int guard = 0;
      while(__hip_atomic_load(&cnt[slot], __ATOMIC_ACQUIRE, __HIP_MEMORY_SCOPE_AGENT) < 4
            && guard < (1<<20)){
        __builtin_amdgcn_s_sleep(8);
        ++guard;
      }
      NRM[0] = __hip_atomic_load(&psum[slot], __ATOMIC_RELAXED, __HIP_MEMORY_SCOPE_AGENT);
    }
    __syncthreads();   // B1
    if(n>0){
      float nr = sqrtf(NRM[0]);
      scale = fminf(nr,100.f)/fmaxf(nr,1e-6f);
    }
    float vcur = pV;
    // ---- prefetch chunk n+1 (drained by B3 before the release-add) ----
    if(n+1<N_){
      int t1 = t0 + C_;
      size_t base1 = base + 4096;
      pW = *(const float4*)(wkop + base1 + (size_t)tid*4);
      pR = *(const float4*)(x + (size_t)(b*T_+t1+c)*D_ + h*64 + 4*q4);
      pIv = invn_g[(size_t)(b*T_+t1+c)*H_ + h];
      pV  = vbuf[(size_t)(b*T_+t1+c)*D_ + h*64 + col0+col];
      if(tid<64){
        pC    = cum_g[((size_t)bh*N_+n+1)*64 + tid];
        pLast = cum_g[((size_t)bh*N_+n+1)*64 + 63];
      }
    }
    // ---- gemv: thread (c,col). S used = scale * ST (lazy) ----
    float da=0.f, dro=0.f;
    #pragma unroll
    for(int q=0;q<16;++q){
      float4 wv = *(const float4*)&WCD[c*68+4*q];
      float4 rr = *(const float4*)&RK [c*68+4*q];
      float4 sv = *(const float4*)&ST [col*68+4*q];
      da  += wv.x*sv.x+wv.y*sv.y+wv.z*sv.z+wv.w*sv.w;
      dro += rr.x*sv.x+rr.y*sv.y+rr.z*sv.z+rr.w*sv.w;
    }
    float vn = vcur - scale*da;
    vbuf[(size_t)(b*T_+t0+c)*D_ + h*64 + col0+col] = vn;
    wkop[base + c*64 + col0+col] = DEc[c]*scale*dro;
    VNS[col*68+c] = vn*DW[c];
    __syncthreads();   // B2
    if(tid<64) PREV[tid] = RK[63*68+tid];
    // ---- S update: thread (d=c, col): sn = elast*scale*U + sum_c wk*vns ----
    float sold = ST[col*68+c];
    float sn = DEc[63]*scale*sold;
    #pragma unroll
    for(int q=0;q<16;++q){
      float4 wt = *(const float4*)&WKT[c*68+4*q];
      float4 vt = *(const float4*)&VNS[col*68+4*q];
      sn += wt.x*vt.x+wt.y*vt.y+wt.z*vt.z+wt.w*vt.w;
    }
    float p = sn*sn;
    p = wave_sum(p);
    if(l==0) P[w]=p;
    __syncthreads();   // B3 (drains vmcnt: prefetches landed before release)
    if(tid==0 && n+1<N_){
      float pl=0.f;
      #pragma unroll
      for(int i=0;i<16;++i) pl += P[i];
      int slot = bh*N_ + n;
      __hip_atomic_fetch_add(&psum[slot], pl, __ATOMIC_RELAXED, __HIP_MEMORY_SCOPE_AGENT);
      __hip_atomic_fetch_add(&cnt[slot], 1, __ATOMIC_RELEASE, __HIP_MEMORY_SCOPE_AGENT);
    }
    ST[col*68+c] = sn;   // unscaled; next gemv applies scale
  }
}

// ---------------------------------------------------------------------------
// K5: o = gate*(opart + intra @ v_new); intra recomputed from rk/wk; o in-place
// ---------------------------------------------------------------------------
__global__ __launch_bounds__(256) void k_o(const float* __restrict__ x,
    const float* __restrict__ invn, const float* __restrict__ cum_g,
    const float* __restrict__ wkop, const float* __restrict__ gate_g,
    float* __restrict__ vbuf){
  int bid = blockIdx.x; int n = bid&63, h=(bid>>6)&15, b=bid>>10;
  int t0 = n*C_;
  __shared__ float sm[8256];
  float* RK = sm;        // 64x64 rk chunk, later INT (intra)
  float* VN = sm+4096;   // 64x64 v_new chunk
  float* CU = sm+8192;   // 64
  float* INT = RK;
  int tid=threadIdx.x, w=tid>>6, l=tid&63;
  if(tid<64) CU[tid] = cum_g[(size_t)bid*64 + tid];
  #pragma unroll 1
  for(int it=0;it<16;++it){
    int idx = tid+256*it; int c=idx>>6, dd=idx&63;
    size_t rr = (size_t)(b*T_+t0+c);
    RK[c*64+dd] = x[rr*D_ + h*64 + dd] * invn[rr*H_ + h];
    VN[idx]     = vbuf[rr*D_ + h*64 + dd];
  }
  __syncthreads();
  float wkj[64];
  {
    int tw = t0+l-1;
    if(tw>=0){
      size_t r2 = (size_t)(b*T_+tw);
      float iv = invn[r2*H_ + h];
      #pragma unroll
      for(int d4=0; d4<16; ++d4){
        float4 u = *(const float4*)(x + r2*D_ + h*64 + 4*d4);
        wkj[4*d4+0]=u.x*iv; wkj[4*d4+1]=u.y*iv;
        wkj[4*d4+2]=u.z*iv; wkj[4*d4+3]=u.w*iv;
      }
    } else {
      #pragma unroll
      for(int dd=0;dd<64;++dd) wkj[dd]=0.f;
    }
  }
  #pragma unroll 1
  for(int it=0;it<16;++it){
    int i = w + 4*it;
    float ar = 0.f;
    #pragma unroll
    for(int d4=0; d4<16; ++d4){
      float4 r4 = *(const float4*)&RK[i*64 + 4*d4];
      ar += r4.x*wkj[4*d4] + r4.y*wkj[4*d4+1] + r4.z*wkj[4*d4+2] + r4.w*wkj[4*d4+3];
    }
    float val = (l<=i) ? (ar*expf(CU[i]-CU[l])) : 0.f;
    INT[i*64+l] = val;
  }
  __syncthreads();
  float vn_col[64];
  #pragma unroll
  for(int k=0;k<64;++k) vn_col[k] = VN[k*64+l];
  #pragma unroll 1
  for(int it=0;it<16;++it){
    int c = w+4*it;
    float acc = 0.f;
    #pragma unroll
    for(int d4=0; d4<16; ++d4){
      float4 i4 = *(const float4*)&INT[c*64 + 4*d4];
      acc += i4.x*vn_col[4*d4] + i4.y*vn_col[4*d4+1] + i4.z*vn_col[4*d4+2] + i4.w*vn_col[4*d4+3];
    }
    size_t rr = (size_t)(b*T_+t0+c);
    float g  = gate_g[rr*H_ + h];
    float op = wkop[(size_t)bid*4096 + c*64 + l];
    vbuf[rr*D_ + h*64 + l] = (op + acc)*g;
  }
}

// ---------------------------------------------------------------------------
extern "C" void kernel_launch(void* const* d_in, const int* in_sizes, int n_in,
                              void* d_out, int out_size, void* d_ws, size_t ws_size,
                              hipStream_t stream) {
  const float* x       = (const float*)d_in[0];
  const float* w_write = (const float*)d_in[1];
  const float* w_gate  = (const float*)d_in[2];
  const float* w_out   = (const float*)d_in[3];
  const float* w_beta  = (const float*)d_in[4];
  const float* w_alpha = (const float*)d_in[5];
  const float* dt_bias = (const float*)d_in[6];
  const float* A_log   = (const float*)d_in[7];
  float* outp = (float*)d_out;

  const size_t big   = (size_t)BT_*D_;   // 16,777,216 floats
  const size_t small = (size_t)BT_*H_;   //    262,144 floats
  const size_t nslot = (size_t)B_*H_*N_; //       4096 team-sync slots
  const size_t need  = (2*big + 5*small + 2*nslot)*sizeof(float);
  if(ws_size < need) return;   // diagnostic: wrong-answer instead of fault

  float* ws   = (float*)d_ws;
  float* vbuf = ws;              // v -> v_corr -> v_new -> o
  float* wkop = vbuf + big;      // wk_cd -> opart
  float* invn = wkop + big;
  float* gate = invn + small;
  float* beta = gate + small;
  float* dec  = beta + small;
  float* cum  = dec  + small;
  float* psum = cum  + small;
  int*   cnt  = (int*)(psum + nslot);

  k_small<<<dim3(BT_/KSR), dim3(256), 0, stream>>>(x, w_gate, w_beta, w_alpha,
      dt_bias, A_log, invn, gate, beta, dec);
  k_gemm_bb<<<dim3(D_/BN, BT_/BM), dim3(256), 0, stream>>>(x, w_write, vbuf,
      BT_, D_, D_);
  k_chunk<<<dim3(B_*H_*N_), dim3(256), 0, stream>>>(x, invn, beta, dec,
      cum, vbuf, wkop, psum, cnt);
  k_scan<<<dim3(4*B_*H_), dim3(1024), 0, stream>>>(x, invn, cum, vbuf, wkop,
      psum, cnt);
  k_o<<<dim3(B_*H_*N_), dim3(256), 0, stream>>>(x, invn, cum, wkop, gate, vbuf);
  k_gemm_out<<<dim3(D_/BN, BT_/BM), dim3(256), 0, stream>>>(vbuf, w_out, x,
      outp, BT_, D_, D_);
}

// Round 5
// 1249.466 us; speedup vs baseline: 3.6028x; 1.4672x over previous
//
#include <hip/hip_runtime.h>
#include <stdint.h>

#define B_ 4
#define T_ 4096
#define D_ 1024
#define H_ 16
#define HD_ 64
#define C_ 64
#define N_ 64
#define BT_ (B_*T_)

typedef _Float16 f16;
typedef f16 f16x4 __attribute__((ext_vector_type(4)));
typedef f16 f16x8 __attribute__((ext_vector_type(8)));
typedef float f32x4 __attribute__((ext_vector_type(4)));

__device__ __forceinline__ float wave_sum(float v){
  #pragma unroll
  for(int off=32; off>0; off>>=1) v += __shfl_down(v, off);
  return __shfl(v, 0);
}

// ---------------------------------------------------------------------------
// K1 v2: tiled skinny GEMM (16 rows/block, 256 thr).
// ---------------------------------------------------------------------------
#define KSR 16   // rows per block
__global__ __launch_bounds__(256) void k_small(const float* __restrict__ x,
    const float* __restrict__ wg, const float* __restrict__ wb, const float* __restrict__ wa,
    const float* __restrict__ dtb, const float* __restrict__ alog,
    float* __restrict__ invn, float* __restrict__ gate, float* __restrict__ beta,
    float* __restrict__ dec){
  __shared__ float Xs [KSR][68];
  __shared__ float Wgt[H_ ][68];
  __shared__ float Wbt[H_ ][68];
  __shared__ float Wat[H_ ][68];
  int tid = threadIdx.x;
  int r = tid>>4, h = tid&15;
  int row0 = blockIdx.x*KSR;

  int sr = tid>>4, sf = (tid&15);      // x: row sr, float4 slot sf
  int wk = tid>>2, wj = tid&3;         // W: k row wk, float4 col slot wj

  float dg=0.f, db=0.f, da=0.f, ss=0.f;

  float4 px = *(const float4*)(x + (size_t)(row0+sr)*D_ + sf*4);
  float4 pg = *(const float4*)(wg + (size_t)wk*H_ + 4*wj);
  float4 pb = *(const float4*)(wb + (size_t)wk*H_ + 4*wj);
  float4 pa = *(const float4*)(wa + (size_t)wk*H_ + 4*wj);

  for(int t=0; t<16; ++t){
    __syncthreads();
    *(float4*)&Xs[sr][sf*4] = px;
    Wgt[4*wj+0][wk]=pg.x; Wgt[4*wj+1][wk]=pg.y; Wgt[4*wj+2][wk]=pg.z; Wgt[4*wj+3][wk]=pg.w;
    Wbt[4*wj+0][wk]=pb.x; Wbt[4*wj+1][wk]=pb.y; Wbt[4*wj+2][wk]=pb.z; Wbt[4*wj+3][wk]=pb.w;
    Wat[4*wj+0][wk]=pa.x; Wat[4*wj+1][wk]=pa.y; Wat[4*wj+2][wk]=pa.z; Wat[4*wj+3][wk]=pa.w;
    if(t<15){
      int k0 = (t+1)*64;
      px = *(const float4*)(x + (size_t)(row0+sr)*D_ + k0 + sf*4);
      pg = *(const float4*)(wg + (size_t)(k0+wk)*H_ + 4*wj);
      pb = *(const float4*)(wb + (size_t)(k0+wk)*H_ + 4*wj);
      pa = *(const float4*)(wa + (size_t)(k0+wk)*H_ + 4*wj);
    }
    __syncthreads();
    #pragma unroll
    for(int q=0;q<16;++q){
      float4 xv = *(const float4*)&Xs[r][4*q];
      float4 g4 = *(const float4*)&Wgt[h][4*q];
      float4 b4 = *(const float4*)&Wbt[h][4*q];
      float4 a4 = *(const float4*)&Wat[h][4*q];
      dg += xv.x*g4.x + xv.y*g4.y + xv.z*g4.z + xv.w*g4.w;
      db += xv.x*b4.x + xv.y*b4.y + xv.z*b4.z + xv.w*b4.w;
      da += xv.x*a4.x + xv.y*a4.y + xv.z*a4.z + xv.w*a4.w;
      if(t==h) ss += xv.x*xv.x + xv.y*xv.y + xv.z*xv.z + xv.w*xv.w;
    }
  }

  int o = row0*H_ + tid;
  invn[o] = 1.f/fmaxf(sqrtf(ss),1e-12f);
  gate[o] = 1.f/(1.f+expf(-dg));
  beta[o] = 1.f/(1.f+expf(-db));
  float z = da + dtb[h];
  float sp = (z>20.f)? z : log1pf(expf(z));
  dec[o] = -expf(alog[h])*sp;
}

// ---------------------------------------------------------------------------
// K_TR: wt[n][k] = (f16)w[k][n], 1024x1024. 64x64 tile per block via LDS.
// ---------------------------------------------------------------------------
__global__ __launch_bounds__(256) void k_tr(const float* __restrict__ w,
    f16* __restrict__ wt){
  __shared__ float T[64*68];
  int tid = threadIdx.x;
  int bj = blockIdx.x, bi = blockIdx.y;   // bi: k-tile, bj: n-tile
  #pragma unroll
  for(int j=0;j<4;++j){
    int idx = tid + 256*j;
    int r = idx>>4, q = idx&15;
    float4 u = *(const float4*)(w + (size_t)(bi*64+r)*1024 + bj*64 + 4*q);
    T[(4*q+0)*68 + r] = u.x;
    T[(4*q+1)*68 + r] = u.y;
    T[(4*q+2)*68 + r] = u.z;
    T[(4*q+3)*68 + r] = u.w;
  }
  __syncthreads();
  int cc = tid>>2, seg = tid&3;
  f16 h[16];
  #pragma unroll
  for(int u2=0;u2<4;++u2){
    float4 f = *(const float4*)&T[cc*68 + seg*16 + 4*u2];
    h[4*u2+0]=(f16)f.x; h[4*u2+1]=(f16)f.y; h[4*u2+2]=(f16)f.z; h[4*u2+3]=(f16)f.w;
  }
  size_t o = (size_t)(bj*64+cc)*1024 + bi*64 + seg*16;
  *(f16x8*)(wt + o)     = *(f16x8*)&h[0];
  *(f16x8*)(wt + o + 8) = *(f16x8*)&h[8];
}

// ---------------------------------------------------------------------------
// K_GEMM16: C(f32) = A(f32, cast f16) @ BT^T (+resid). MFMA 16x16x32_f16.
//   A [M][1024] f32 row-major; BT [1024][1024] f16 = B^T (rows = output col n).
//   128x128 tile, BK=64, 4 waves (2x2 of 64x64), 4x4 frags/wave.
//   LDS rows padded to 72 halves -> uniform bank-quad b128 frag reads.
// ---------------------------------------------------------------------------
__global__ __launch_bounds__(256) void k_gemm16(const float* __restrict__ A,
    const f16* __restrict__ BT, const float* __restrict__ resid,
    float* __restrict__ C, int addres){
  __shared__ f16 Al[128*72];
  __shared__ f16 Bl[128*72];
  int tid = threadIdx.x;
  int m0 = blockIdx.y*128, n0 = blockIdx.x*128;
  int w = tid>>6, l = tid&63;
  int wm = (w>>1)*64, wn = (w&1)*64;
  int lr = l&15, lq = l>>4;
  f32x4 acc[4][4] = {};
  for(int k0=0; k0<1024; k0+=64){
    __syncthreads();   // previous compute done reading LDS
    // stage A: 128x64 f32 -> f16 (coalesced float4 loads, b64 LDS writes)
    #pragma unroll
    for(int j=0;j<8;++j){
      int idx = tid + 256*j;
      int m = idx>>4, q = idx&15;
      float4 u = *(const float4*)(A + (size_t)(m0+m)*1024 + k0 + 4*q);
      f16x4 hv; hv[0]=(f16)u.x; hv[1]=(f16)u.y; hv[2]=(f16)u.z; hv[3]=(f16)u.w;
      *(f16x4*)&Al[m*72 + 4*q] = hv;
    }
    // stage B: BT rows (f16 direct, 16B loads, b128 LDS writes)
    #pragma unroll
    for(int j=0;j<4;++j){
      int idx = tid + 256*j;
      int n = idx>>3, o8 = idx&7;
      f16x8 hv = *(const f16x8*)(BT + (size_t)(n0+n)*1024 + k0 + 8*o8);
      *(f16x8*)&Bl[n*72 + 8*o8] = hv;
    }
    __syncthreads();
    #pragma unroll
    for(int kb=0; kb<64; kb+=32){
      f16x8 a[4], b[4];
      #pragma unroll
      for(int i=0;i<4;++i){
        a[i] = *(const f16x8*)&Al[(wm + i*16 + lr)*72 + kb + 8*lq];
        b[i] = *(const f16x8*)&Bl[(wn + i*16 + lr)*72 + kb + 8*lq];
      }
      #pragma unroll
      for(int mi=0;mi<4;++mi)
        #pragma unroll
        for(int ni=0;ni<4;++ni)
          acc[mi][ni] = __builtin_amdgcn_mfma_f32_16x16x32_f16(a[mi], b[ni], acc[mi][ni], 0,0,0);
    }
  }
  // epilogue: row = wm+mi*16+lq*4+r, col = wn+ni*16+lr
  #pragma unroll
  for(int mi=0;mi<4;++mi){
    #pragma unroll
    for(int r=0;r<4;++r){
      int m = m0 + wm + mi*16 + lq*4 + r;
      #pragma unroll
      for(int ni=0;ni<4;++ni){
        int n = n0 + wn + ni*16 + lr;
        size_t o = (size_t)m*1024 + n;
        float v = acc[mi][ni][r];
        if(addres) v += resid[o];
        C[o] = v;
      }
    }
  }
}

// ---------------------------------------------------------------------------
// K3: per-chunk: cum, KK, forward substitution -> v_corr (in-place in vbuf),
//     wk_cd -> wkop. Also zeroes this chunk's psum/cnt team-sync slot.
// ---------------------------------------------------------------------------
__global__ __launch_bounds__(256) void k_chunk(const float* __restrict__ x,
    const float* __restrict__ invn, const float* __restrict__ beta_g,
    const float* __restrict__ dec_g, float* __restrict__ cum_g,
    float* __restrict__ vbuf, float* __restrict__ wkop,
    float* __restrict__ psum, int* __restrict__ cnt){
  int bid = blockIdx.x;                  // b*H*N + h*N + n  == bh*64 + n
  int n = bid & 63; int h = (bid>>6) & 15; int b = bid>>10;
  int t0 = n*C_;
  __shared__ float sm[12608];
  float* WK = sm;            // 64*65 (padded), aliased by XV later
  float* KK = sm+4160;       // 64*64
  float* XW = sm+8256;       // 64*64
  float* BS = sm+12352;      // 64
  float* CU = sm+12416;      // 64
  float* DE = sm+12480;      // 64
  float* GS = sm+12544;      // 64
  float* XV = WK;            // 4096 over WK region (stride 64)
  int tid = threadIdx.x, w = tid>>6, l = tid&63;
  if(tid==0){ psum[bid]=0.f; cnt[bid]=0; }   // reset team-sync slot for k_scan
  // A: stage shifted normalized keys + beta + decay
  #pragma unroll
  for(int it=0; it<16; ++it){
    int idx = tid + 256*it; int c = idx>>6, dd = idx&63;
    int tw = t0+c-1;
    float wv = 0.f;
    if(tw>=0){
      size_t rr = (size_t)(b*T_+tw);
      wv = x[rr*D_ + h*64 + dd] * invn[rr*H_ + h];
    }
    WK[c*65+dd] = wv;
  }
  if(tid<64){
    size_t rr = (size_t)(b*T_+t0+tid);
    BS[tid] = beta_g[rr*H_+h];
    GS[tid] = dec_g[rr*H_+h];
  }
  __syncthreads();
  // B: inclusive cumsum of decay (wave 0)
  if(w==0){
    float xg = GS[l];
    #pragma unroll
    for(int off=1; off<64; off<<=1){
      float y = __shfl_up(xg, off);
      if(l>=off) xg += y;
    }
    CU[l]=xg; DE[l]=expf(xg);
    cum_g[(size_t)bid*64 + l] = xg;
  }
  __syncthreads();
  // C: KK[i][j] = beta_i * (wk_i . wk_j) * L[i][j], strict lower
  float wkj[64];
  #pragma unroll
  for(int dd=0; dd<64; ++dd) wkj[dd] = WK[l*65+dd];
  #pragma unroll 1
  for(int it=0; it<16; ++it){
    int i = w + 4*it;
    float aw=0.f;
    #pragma unroll
    for(int dd=0; dd<64; ++dd) aw += WK[i*65+dd]*wkj[dd];
    KK[i*64+l] = (l<i) ? (BS[i]*aw*expf(CU[i]-CU[l])) : 0.f;
  }
  __syncthreads();
  // D: capture rhs into regs, then write XV (over WK), XW
  float rv[16], rw[16];
  #pragma unroll
  for(int it=0; it<16; ++it){
    int i = w + 4*it;
    rw[it] = WK[i*65+l]*BS[i]*DE[i];
    rv[it] = vbuf[(size_t)(b*T_+t0+i)*D_ + h*64 + l]*BS[i];
  }
  __syncthreads();
  #pragma unroll
  for(int it=0; it<16; ++it){
    int i = w + 4*it;
    XV[i*64+l] = rv[it];
    XW[i*64+l] = rw[it];
  }
  __syncthreads();
  // E: forward substitution (I + strict_lower(KK)) X = rhs (waves 0,1)
  if(w<2){
    float* Xc = (w==0) ? XV : XW;
    for(int i=1;i<64;++i){
      float acc = Xc[i*64+l];
      for(int k=0;k<i;++k) acc -= KK[i*64+k]*Xc[k*64+l];
      Xc[i*64+l] = acc;
    }
  }
  __syncthreads();
  // F: write v_corr (in place), wk_cd
  #pragma unroll
  for(int it=0; it<16; ++it){
    int i = w + 4*it;
    vbuf[(size_t)(b*T_+t0+i)*D_ + h*64 + l] = XV[i*64+l];
    wkop[(size_t)bid*4096 + i*64 + l]       = XW[i*64+l];
  }
}

// ---------------------------------------------------------------------------
// K4 v4b: column-split team scan (unchanged from round 4, verified).
// ---------------------------------------------------------------------------
__global__ __launch_bounds__(1024, 4) void k_scan(const float* __restrict__ x,
    const float* __restrict__ invn_g, const float* __restrict__ cum_g,
    float* __restrict__ vbuf, float* __restrict__ wkop,
    float* __restrict__ psum, int* __restrict__ cnt){
  int bh = blockIdx.x & 63, cg = blockIdx.x >> 6;
  int b = bh>>4, h = bh&15, col0 = cg*16;
  __shared__ float sm[15448];
  float* WCD = sm;           // [64][68] wkcd rows
  float* RK  = sm+4352;      // [64][68] rk rows (scaled by invn)
  float* WKT = sm+8704;      // [64][68] WKT[d][c] = wk[c][d] (col 0 = PREV)
  float* VNS = sm+13056;     // [16][68] VNS[col][c] = v_new*DW, transposed
  float* ST  = sm+14144;     // [16][68] ST[col][d] = S (UNSCALED U), transposed
  float* DW  = sm+15232;     // 64: exp(last-cum)
  float* DEc = sm+15296;     // 64: exp(cum)
  float* PREV= sm+15360;     // 64: prev chunk's last rk row
  float* P   = sm+15424;     // 16
  float* NRM = sm+15440;     // 1
  int tid = threadIdx.x, w = tid>>6, l = tid&63;
  int c = tid>>4, q4 = tid&15;     // row / float4-slot (stage)
  int col = tid&15;                // local column (compute)

  for(int i=tid;i<1088;i+=1024) ST[i]=0.f;
  if(tid<64) PREV[tid]=0.f;

  // prologue prefetch chunk 0
  float4 pW, pR; float pIv, pV, pC=0.f, pLast=0.f;
  {
    size_t base0 = (size_t)bh*N_*4096;
    pW = *(const float4*)(wkop + base0 + (size_t)tid*4);
    pR = *(const float4*)(x + (size_t)(b*T_+c)*D_ + h*64 + 4*q4);
    pIv = invn_g[(size_t)(b*T_+c)*H_ + h];
    pV  = vbuf[(size_t)(b*T_+c)*D_ + h*64 + col0+col];
    if(tid<64){
      pC    = cum_g[(size_t)bh*N_*64 + tid];
      pLast = cum_g[(size_t)bh*N_*64 + 63];
    }
  }
  __syncthreads();

  float scale = 1.f;
  for(int n=0;n<N_;++n){
    int t0 = n*C_;
    size_t base = ((size_t)bh*N_+n)*4096;
    // ---- stage ----
    *(float4*)&WCD[c*68+4*q4] = pW;
    float4 rv4;
    rv4.x=pR.x*pIv; rv4.y=pR.y*pIv; rv4.z=pR.z*pIv; rv4.w=pR.w*pIv;
    *(float4*)&RK[c*68+4*q4] = rv4;
    if(c<63){
      WKT[(4*q4+0)*68 + c+1]=rv4.x;
      WKT[(4*q4+1)*68 + c+1]=rv4.y;
      WKT[(4*q4+2)*68 + c+1]=rv4.z;
      WKT[(4*q4+3)*68 + c+1]=rv4.w;
    }
    if(tid<64){
      WKT[tid*68+0] = PREV[tid];
      DW[tid]  = expf(pLast-pC);
      DEc[tid] = expf(pC);
    }
    // ---- bounded spin for previous chunk's team norm ----
    if(n>0 && tid==0){
      int slot = bh*N_ + n-1;
      int guard = 0;
      while(__hip_atomic_load(&cnt[slot], __ATOMIC_ACQUIRE, __HIP_MEMORY_SCOPE_AGENT) < 4
            && guard < (1<<20)){
        __builtin_amdgcn_s_sleep(8);
        ++guard;
      }
      NRM[0] = __hip_atomic_load(&psum[slot], __ATOMIC_RELAXED, __HIP_MEMORY_SCOPE_AGENT);
    }
    __syncthreads();   // B1
    if(n>0){
      float nr = sqrtf(NRM[0]);
      scale = fminf(nr,100.f)/fmaxf(nr,1e-6f);
    }
    float vcur = pV;
    // ---- prefetch chunk n+1 (drained by B3 before the release-add) ----
    if(n+1<N_){
      int t1 = t0 + C_;
      size_t base1 = base + 4096;
      pW = *(const float4*)(wkop + base1 + (size_t)tid*4);
      pR = *(const float4*)(x + (size_t)(b*T_+t1+c)*D_ + h*64 + 4*q4);
      pIv = invn_g[(size_t)(b*T_+t1+c)*H_ + h];
      pV  = vbuf[(size_t)(b*T_+t1+c)*D_ + h*64 + col0+col];
      if(tid<64){
        pC    = cum_g[((size_t)bh*N_+n+1)*64 + tid];
        pLast = cum_g[((size_t)bh*N_+n+1)*64 + 63];
      }
    }
    // ---- gemv: thread (c,col). S used = scale * ST (lazy) ----
    float da=0.f, dro=0.f;
    #pragma unroll
    for(int q=0;q<16;++q){
      float4 wv = *(const float4*)&WCD[c*68+4*q];
      float4 rr = *(const float4*)&RK [c*68+4*q];
      float4 sv = *(const float4*)&ST [col*68+4*q];
      da  += wv.x*sv.x+wv.y*sv.y+wv.z*sv.z+wv.w*sv.w;
      dro += rr.x*sv.x+rr.y*sv.y+rr.z*sv.z+rr.w*sv.w;
    }
    float vn = vcur - scale*da;
    vbuf[(size_t)(b*T_+t0+c)*D_ + h*64 + col0+col] = vn;
    wkop[base + c*64 + col0+col] = DEc[c]*scale*dro;
    VNS[col*68+c] = vn*DW[c];
    __syncthreads();   // B2
    if(tid<64) PREV[tid] = RK[63*68+tid];
    // ---- S update ----
    float sold = ST[col*68+c];
    float sn = DEc[63]*scale*sold;
    #pragma unroll
    for(int q=0;q<16;++q){
      float4 wt = *(const float4*)&WKT[c*68+4*q];
      float4 vt = *(const float4*)&VNS[col*68+4*q];
      sn += wt.x*vt.x+wt.y*vt.y+wt.z*vt.z+wt.w*vt.w;
    }
    float p = sn*sn;
    p = wave_sum(p);
    if(l==0) P[w]=p;
    __syncthreads();   // B3 (drains vmcnt: prefetches landed before release)
    if(tid==0 && n+1<N_){
      float pl=0.f;
      #pragma unroll
      for(int i=0;i<16;++i) pl += P[i];
      int slot = bh*N_ + n;
      __hip_atomic_fetch_add(&psum[slot], pl, __ATOMIC_RELAXED, __HIP_MEMORY_SCOPE_AGENT);
      __hip_atomic_fetch_add(&cnt[slot], 1, __ATOMIC_RELEASE, __HIP_MEMORY_SCOPE_AGENT);
    }
    ST[col*68+c] = sn;   // unscaled; next gemv applies scale
  }
}

// ---------------------------------------------------------------------------
// K5: o = gate*(opart + intra @ v_new); intra recomputed from rk/wk; o in-place
// ---------------------------------------------------------------------------
__global__ __launch_bounds__(256) void k_o(const float* __restrict__ x,
    const float* __restrict__ invn, const float* __restrict__ cum_g,
    const float* __restrict__ wkop, const float* __restrict__ gate_g,
    float* __restrict__ vbuf){
  int bid = blockIdx.x; int n = bid&63, h=(bid>>6)&15, b=bid>>10;
  int t0 = n*C_;
  __shared__ float sm[8256];
  float* RK = sm;        // 64x64 rk chunk, later INT (intra)
  float* VN = sm+4096;   // 64x64 v_new chunk
  float* CU = sm+8192;   // 64
  float* INT = RK;
  int tid=threadIdx.x, w=tid>>6, l=tid&63;
  if(tid<64) CU[tid] = cum_g[(size_t)bid*64 + tid];
  #pragma unroll 1
  for(int it=0;it<16;++it){
    int idx = tid+256*it; int c=idx>>6, dd=idx&63;
    size_t rr = (size_t)(b*T_+t0+c);
    RK[c*64+dd] = x[rr*D_ + h*64 + dd] * invn[rr*H_ + h];
    VN[idx]     = vbuf[rr*D_ + h*64 + dd];
  }
  __syncthreads();
  float wkj[64];
  {
    int tw = t0+l-1;
    if(tw>=0){
      size_t r2 = (size_t)(b*T_+tw);
      float iv = invn[r2*H_ + h];
      #pragma unroll
      for(int d4=0; d4<16; ++d4){
        float4 u = *(const float4*)(x + r2*D_ + h*64 + 4*d4);
        wkj[4*d4+0]=u.x*iv; wkj[4*d4+1]=u.y*iv;
        wkj[4*d4+2]=u.z*iv; wkj[4*d4+3]=u.w*iv;
      }
    } else {
      #pragma unroll
      for(int dd=0;dd<64;++dd) wkj[dd]=0.f;
    }
  }
  #pragma unroll 1
  for(int it=0;it<16;++it){
    int i = w + 4*it;
    float ar = 0.f;
    #pragma unroll
    for(int d4=0; d4<16; ++d4){
      float4 r4 = *(const float4*)&RK[i*64 + 4*d4];
      ar += r4.x*wkj[4*d4] + r4.y*wkj[4*d4+1] + r4.z*wkj[4*d4+2] + r4.w*wkj[4*d4+3];
    }
    float val = (l<=i) ? (ar*expf(CU[i]-CU[l])) : 0.f;
    INT[i*64+l] = val;
  }
  __syncthreads();
  float vn_col[64];
  #pragma unroll
  for(int k=0;k<64;++k) vn_col[k] = VN[k*64+l];
  #pragma unroll 1
  for(int it=0;it<16;++it){
    int c = w+4*it;
    float acc = 0.f;
    #pragma unroll
    for(int d4=0; d4<16; ++d4){
      float4 i4 = *(const float4*)&INT[c*64 + 4*d4];
      acc += i4.x*vn_col[4*d4] + i4.y*vn_col[4*d4+1] + i4.z*vn_col[4*d4+2] + i4.w*vn_col[4*d4+3];
    }
    size_t rr = (size_t)(b*T_+t0+c);
    float g  = gate_g[rr*H_ + h];
    float op = wkop[(size_t)bid*4096 + c*64 + l];
    vbuf[rr*D_ + h*64 + l] = (op + acc)*g;
  }
}

// ---------------------------------------------------------------------------
extern "C" void kernel_launch(void* const* d_in, const int* in_sizes, int n_in,
                              void* d_out, int out_size, void* d_ws, size_t ws_size,
                              hipStream_t stream) {
  const float* x       = (const float*)d_in[0];
  const float* w_write = (const float*)d_in[1];
  const float* w_gate  = (const float*)d_in[2];
  const float* w_out   = (const float*)d_in[3];
  const float* w_beta  = (const float*)d_in[4];
  const float* w_alpha = (const float*)d_in[5];
  const float* dt_bias = (const float*)d_in[6];
  const float* A_log   = (const float*)d_in[7];
  float* outp = (float*)d_out;

  const size_t big   = (size_t)BT_*D_;   // 16,777,216 floats
  const size_t small = (size_t)BT_*H_;   //    262,144 floats
  const size_t nslot = (size_t)B_*H_*N_; //       4096 team-sync slots
  const size_t wsz   = (size_t)D_*D_;    //  1,048,576 halves per weight
  const size_t need  = (2*big + 5*small + 2*nslot)*sizeof(float) + 2*wsz*sizeof(f16);
  if(ws_size < need) return;   // diagnostic: wrong-answer instead of fault

  float* ws   = (float*)d_ws;
  float* vbuf = ws;              // v -> v_corr -> v_new -> o
  float* wkop = vbuf + big;      // wk_cd -> opart
  float* invn = wkop + big;
  float* gate = invn + small;
  float* beta = gate + small;
  float* dec  = beta + small;
  float* cum  = dec  + small;
  float* psum = cum  + small;
  int*   cnt  = (int*)(psum + nslot);
  f16*   wtw  = (f16*)(cnt + nslot);     // w_write^T in f16 [n][k]
  f16*   wto  = wtw + wsz;               // w_out^T   in f16 [n][k]

  k_tr<<<dim3(16,16), dim3(256), 0, stream>>>(w_write, wtw);
  k_tr<<<dim3(16,16), dim3(256), 0, stream>>>(w_out,  wto);
  k_small<<<dim3(BT_/KSR), dim3(256), 0, stream>>>(x, w_gate, w_beta, w_alpha,
      dt_bias, A_log, invn, gate, beta, dec);
  k_gemm16<<<dim3(D_/128, BT_/128), dim3(256), 0, stream>>>(x, wtw,
      (const float*)0, vbuf, 0);
  k_chunk<<<dim3(B_*H_*N_), dim3(256), 0, stream>>>(x, invn, beta, dec,
      cum, vbuf, wkop, psum, cnt);
  k_scan<<<dim3(4*B_*H_), dim3(1024), 0, stream>>>(x, invn, cum, vbuf, wkop,
      psum, cnt);
  k_o<<<dim3(B_*H_*N_), dim3(256), 0, stream>>>(x, invn, cum, wkop, gate, vbuf);
  k_gemm16<<<dim3(D_/128, BT_/128), dim3(256), 0, stream>>>(vbuf, wto, x,
      outp, 1);
}